// Round 4
// baseline (828.297 us; speedup 1.0000x reference)
//
#include <hip/hip_runtime.h>

// SCAM fused kernel for MI355X (gfx950).
// R4: persistent workgroups (256 WGs x 6 slices each) + cross-slice staging
// prefetch (T14 async-STAGE split): slice i+1's global x loads are issued at
// the top of slice i's compute and consumed at the next loop head. W1 frags
// un-hoisted to keep VGPR <= 170 (12 waves must co-reside). R3 swizzles kept.

typedef __attribute__((ext_vector_type(8))) short bhalf8;   // 8 bf16 in 4 VGPRs
typedef __attribute__((ext_vector_type(4))) float f32x4;

#define DEVI static __device__ __forceinline__

constexpr int Cc   = 192;
constexpr int HWc  = 9216;          // 96*96
constexpr int CHW  = 192 * 9216;    // per-batch image
constexpr int HALF_OUT = 16 * CHW;  // 28311552
constexpr int PS   = 104;           // padded row stride (halves) for P and Vt
constexpr int AS   = 100;           // att row stride (dwords)

DEVI unsigned short f2bf(float f) {           // round-to-nearest-even fp32->bf16
  unsigned u = __builtin_bit_cast(unsigned, f);
  u += 0x7fffu + ((u >> 16) & 1u);
  return (unsigned short)(u >> 16);
}
DEVI float bf2f(unsigned short h) {
  unsigned u = (unsigned)h << 16;
  return __builtin_bit_cast(float, u);
}
DEVI float bf2f_s(short h) { return bf2f((unsigned short)h); }

// ---------------------------------------------------------------- setup 1 ---
__global__ void setup1(
    const float* __restrict__ t,
    const float* __restrict__ lnwl, const float* __restrict__ lnbl,
    const float* __restrict__ lnwr, const float* __restrict__ lnbr,
    const float* __restrict__ Wl1, const float* __restrict__ bl1,
    const float* __restrict__ Wr1, const float* __restrict__ br1,
    const float* __restrict__ Wl2, const float* __restrict__ Wr2,
    short* __restrict__ W1l_b, short* __restrict__ W1r_b,
    short* __restrict__ W2l_b, short* __restrict__ W2r_b,
    float* __restrict__ s1l, float* __restrict__ t1l,
    float* __restrict__ s1r, float* __restrict__ t1r,
    float* __restrict__ mt)
{
  const int blk = blockIdx.x, tid = threadIdx.x;
  if (blk < 576) {
    int id  = blk * 256 + tid;          // < 147456
    int m   = id / 36864;
    int rem = id - m * 36864;
    int c   = rem % 192;
    float v;
    short* dst;
    if (m == 0)      { v = lnwl[c] * Wl1[rem]; dst = W1l_b; }
    else if (m == 1) { v = lnwr[c] * Wr1[rem]; dst = W1r_b; }
    else if (m == 2) { v = Wl2[rem];           dst = W2l_b; }
    else             { v = Wr2[rem];           dst = W2r_b; }
    dst[rem] = (short)f2bf(v);
  } else if (blk == 576 || blk == 577) {
    if (tid < 192) {
      const float* Wm = (blk == 576) ? Wl1 : Wr1;
      const float* lw = (blk == 576) ? lnwl : lnwr;
      const float* lb = (blk == 576) ? lnbl : lnbr;
      const float* bb = (blk == 576) ? bl1 : br1;
      float s = 0.f, tb = 0.f;
      for (int c = 0; c < 192; ++c) {
        float wv = Wm[tid * 192 + c];
        s  += lw[c] * wv;
        tb += lb[c] * wv;
      }
      if (blk == 576) { s1l[tid] = s; t1l[tid] = tb + bb[tid]; }
      else            { s1r[tid] = s; t1r[tid] = tb + bb[tid]; }
    }
  } else {
    int id = (blk - 578) * 256 + tid;   // < 8192
    float v = t[id];
    float sp = (v > 20.f) ? v : log1pf(__expf(v));
    mt[id] = v * tanhf(sp);
  }
}

// temb[b][o] = sum_k mish(t)[b][k] * Wt[o][k] + bt[o]
__global__ void setup2(const float* __restrict__ mt, const float* __restrict__ Wt,
                       const float* __restrict__ bt, float* __restrict__ temb)
{
  int id = blockIdx.x * 256 + threadIdx.x;  // < 3072
  int b = id / 192, o = id - b * 192;
  float s = 0.f;
  for (int k = 0; k < 512; ++k) s += mt[b * 512 + k] * Wt[o * 512 + k];
  temb[id] = s + bt[o];
}

// ------------------------------------------------------------- main kernel ---
// misc layout (floats): 0 mu_l[96], 96 rs_l[96], 192 mu_r[96], 288 rs_r[96],
// 384 te[192], 576 beta[192], 768 gamma[192]   (end 960)
struct SmemT {
  short buf1[96 * 200];   // XT_l -> Q_l -> att(fp32, stride 100dw) -> F_r2l 38400 B
  short buf2[19968];      // XT_r -> Q_r -> P_row/P_colT -> F_l2r            39936 B
  short vtl[192 * PS];    // V_l^T [c][x] stride 104                         39936 B
  short vtr[192 * PS];    // V_r^T [c][y] stride 104                         39936 B
  float misc[960];        //                                                  3840 B
};
static_assert(sizeof(SmemT) <= 163840, "LDS overflow");

__launch_bounds__(768, 3)
__global__ void scam_main(
    const float* __restrict__ x_l, const float* __restrict__ x_r,
    const float* __restrict__ bl2, const float* __restrict__ br2,
    const float* __restrict__ beta, const float* __restrict__ gamma,
    const short* __restrict__ W1l_b, const short* __restrict__ W1r_b,
    const short* __restrict__ W2l_b, const short* __restrict__ W2r_b,
    const float* __restrict__ s1l, const float* __restrict__ t1l,
    const float* __restrict__ s1r, const float* __restrict__ t1r,
    const float* __restrict__ temb,
    float* __restrict__ out)
{
  __shared__ SmemT sm;
  const int tid  = threadIdx.x;
  const int lane = tid & 63;
  const int wid  = tid >> 6;            // 0..11
  const int m16  = lane & 15;
  const int hb   = lane >> 4;           // 0..3
  const int kc8  = hb * 8;              // element offset within a fragment row
  const int r4   = hb * 4;              // D-row base
  const int wg   = blockIdx.x;          // 0..255 persistent WGs
  const int bb_  = wg >> 4;             // batch (16 WGs per batch; 96=16*6)
  const int hh0  = 6 * (wg & 15);       // first h-row of this WG
  const int baseB = bb_ * CHW;
  const int o_wm = wid * 16 + m16;

  // per-lane parameter registers (L2-hot scalar loads, issued once per WG)
  float s1Lr = s1l[o_wm], t1Lr = t1l[o_wm];
  float s1Rr = s1r[o_wm], t1Rr = t1r[o_wm];
  float bvL[4], bvR[4];
  #pragma unroll
  for (int j = 0; j < 4; ++j) {
    bvL[j] = bl2[wid * 16 + r4 + j];
    bvR[j] = br2[wid * 16 + r4 + j];
  }

  // once per WG: te/beta/gamma into LDS (b constant across the WG's 6 slices)
  if (tid < 576) {
    int a = tid / 192, o = tid - a * 192;
    if (a == 0)      sm.misc[384 + o] = temb[bb_ * 192 + o];
    else if (a == 1) sm.misc[576 + o] = beta[o];
    else             sm.misc[768 + o] = gamma[o];
  }

  // prologue: prefetch slice 0's x into registers (consumed at loop head)
  float4 xlp[6], xrp[6];
  {
    const int sb = baseB + hh0 * 96;
    #pragma unroll
    for (int j = 0; j < 6; ++j) {
      int i4 = j * 768 + tid;
      int c  = i4 / 24;
      int w4 = i4 - c * 24;
      xlp[j] = *reinterpret_cast<const float4*>(x_l + sb + c * HWc + w4 * 4);
      xrp[j] = *reinterpret_cast<const float4*>(x_r + sb + c * HWc + w4 * 4);
    }
  }

  #pragma unroll 1
  for (int it = 0; it < 6; ++it) {
    const int hh_ = hh0 + it;
    const int sliceBase = baseB + hh_ * 96;

    // phase 1': prefetched regs -> LDS bf16 [w][c] rows (stride 200), swizzled
    #pragma unroll
    for (int j = 0; j < 6; ++j) {
      int i4 = j * 768 + tid;             // < 4608
      int c  = i4 / 24;
      int w4 = i4 - c * 24;               // (w>>2)&7 = w4&7
      int sw = ((((c >> 3) ^ (w4 & 7)) << 3) | (c & 7));
      int base = w4 * 800 + sw;
      float4 xl4 = xlp[j], xr4 = xrp[j];
      sm.buf1[base      ] = (short)f2bf(xl4.x);
      sm.buf1[base + 200] = (short)f2bf(xl4.y);
      sm.buf1[base + 400] = (short)f2bf(xl4.z);
      sm.buf1[base + 600] = (short)f2bf(xl4.w);
      sm.buf2[base      ] = (short)f2bf(xr4.x);
      sm.buf2[base + 200] = (short)f2bf(xr4.y);
      sm.buf2[base + 400] = (short)f2bf(xr4.z);
      sm.buf2[base + 600] = (short)f2bf(xr4.w);
    }
    // issue next slice's prefetch; latency hides under this slice's compute
    if (it < 5) {
      const int sb = sliceBase + 96;
      #pragma unroll
      for (int j = 0; j < 6; ++j) {
        int i4 = j * 768 + tid;
        int c  = i4 / 24;
        int w4 = i4 - c * 24;
        xlp[j] = *reinterpret_cast<const float4*>(x_l + sb + c * HWc + w4 * 4);
        xrp[j] = *reinterpret_cast<const float4*>(x_r + sb + c * HWc + w4 * 4);
      }
    }
    __syncthreads();

    // phase 2: LN stats per pixel
    {
      int side = (tid >= 384) ? 1 : 0;
      int rest = tid - side * 384;
      int w = rest >> 2;
      int q = rest & 3;
      const short* Xb = side ? sm.buf2 : sm.buf1;
      const int kxw = (w >> 2) & 7;
      float s0 = 0.f, s2 = 0.f;
      #pragma unroll
      for (int mc = 0; mc < 6; ++mc) {
        bhalf8 v = *reinterpret_cast<const bhalf8*>(Xb + w * 200 + (((q * 6 + mc) ^ kxw) << 3));
        #pragma unroll
        for (int e = 0; e < 8; ++e) { float f = bf2f_s(v[e]); s0 += f; s2 += f * f; }
      }
      s0 += __shfl_xor(s0, 1); s2 += __shfl_xor(s2, 1);
      s0 += __shfl_xor(s0, 2); s2 += __shfl_xor(s2, 2);
      if (q == 0) {
        float mu  = s0 * (1.f / 192.f);
        float var = s2 * (1.f / 192.f) - mu * mu;
        float rs  = rsqrtf(var + 1e-6f);
        sm.misc[side * 192 + w]      = mu;
        sm.misc[side * 192 + 96 + w] = rs;
      }
    }

    // phase 3: V^T = W2 * X^T  -> vtl/vtr (stride 104)   (D[m=c][n=x])
    #pragma unroll
    for (int sd = 0; sd < 2; ++sd) {
      const short* Wb = sd ? W2r_b : W2l_b;
      const short* Xb = sd ? sm.buf2 : sm.buf1;
      short* Vt = sd ? sm.vtr : sm.vtl;
      const float* bv = sd ? bvR : bvL;
      bhalf8 af[6];
      #pragma unroll
      for (int k = 0; k < 6; ++k)
        af[k] = *reinterpret_cast<const bhalf8*>(Wb + o_wm * 192 + k * 32 + kc8);
      #pragma unroll
      for (int xi = 0; xi < 6; ++xi) {
        const int row = xi * 16 + m16;
        const int kxr = (row >> 2) & 7;
        const short* Xr = Xb + row * 200;
        f32x4 acc = {0.f, 0.f, 0.f, 0.f};
        #pragma unroll
        for (int k = 0; k < 6; ++k) {
          bhalf8 bfr = *reinterpret_cast<const bhalf8*>(Xr + (((k * 4 + hb) ^ kxr) << 3));
          acc = __builtin_amdgcn_mfma_f32_16x16x32_bf16(af[k], bfr, acc, 0, 0, 0);
        }
        const int xcol = xi * 16 + m16;
        #pragma unroll
        for (int j = 0; j < 4; ++j) {
          int cr = wid * 16 + r4 + j;
          Vt[cr * PS + xcol] = (short)f2bf(acc[j] + bv[j]);
        }
      }
    }

    // phase 4a: Q projections into registers (D[m=x][n=o]); W1 frags in-phase
    f32x4 accQ0[6], accQ1[6];
    {
      bhalf8 bfqL[6], bfqR[6];
      #pragma unroll
      for (int k = 0; k < 6; ++k) {
        bfqL[k] = *reinterpret_cast<const bhalf8*>(W1l_b + o_wm * 192 + k * 32 + kc8);
        bfqR[k] = *reinterpret_cast<const bhalf8*>(W1r_b + o_wm * 192 + k * 32 + kc8);
      }
      #pragma unroll
      for (int mi = 0; mi < 6; ++mi) {
        const int row = mi * 16 + m16;
        const int kxr = (row >> 2) & 7;
        const short* Xr = sm.buf1 + row * 200;
        f32x4 acc = {0.f, 0.f, 0.f, 0.f};
        #pragma unroll
        for (int k = 0; k < 6; ++k) {
          bhalf8 afr = *reinterpret_cast<const bhalf8*>(Xr + (((k * 4 + hb) ^ kxr) << 3));
          acc = __builtin_amdgcn_mfma_f32_16x16x32_bf16(afr, bfqL[k], acc, 0, 0, 0);
        }
        accQ0[mi] = acc;
      }
      #pragma unroll
      for (int mi = 0; mi < 6; ++mi) {
        const int row = mi * 16 + m16;
        const int kxr = (row >> 2) & 7;
        const short* Xr = sm.buf2 + row * 200;
        f32x4 acc = {0.f, 0.f, 0.f, 0.f};
        #pragma unroll
        for (int k = 0; k < 6; ++k) {
          bhalf8 afr = *reinterpret_cast<const bhalf8*>(Xr + (((k * 4 + hb) ^ kxr) << 3));
          acc = __builtin_amdgcn_mfma_f32_16x16x32_bf16(afr, bfqR[k], acc, 0, 0, 0);
        }
        accQ1[mi] = acc;
      }
    }
    __syncthreads();
    // phase 4b: write Q with folded LN affine: Q = rs*acc - mu*rs*s1[o] + t1[o]
    {
      const int o = o_wm;
      const int ob = o & 7;
      #pragma unroll
      for (int sd = 0; sd < 2; ++sd) {
        short* Qb = sd ? sm.buf2 : sm.buf1;
        const float* muA = sm.misc + sd * 192;
        const float* rsA = muA + 96;
        float s1o = sd ? s1Rr : s1Lr;
        float t1o = sd ? t1Rr : t1Lr;
        #pragma unroll
        for (int mi = 0; mi < 6; ++mi) {
          const int kx = (4 * mi + hb) & 7;        // (x>>2)&7 for x = mi*16+r4+j
          const int swo = (((o >> 3) ^ kx) << 3) | ob;
          f32x4 acc = sd ? accQ1[mi] : accQ0[mi];
          #pragma unroll
          for (int j = 0; j < 4; ++j) {
            int x = mi * 16 + r4 + j;
            float mu = muA[x], rs = rsA[x];
            Qb[x * 200 + swo] = (short)f2bf(rs * acc[j] - mu * rs * s1o + t1o);
          }
        }
      }
    }
    __syncthreads();

    // phase 5: att = Q_l * Q_r^T (scaled) -> fp32 over buf1, stride 100 dw,
    // column swizzle y ^ (x&31)
    {
      const int mi = wid >> 1;
      const int yb = (wid & 1) * 3;
      const int arow = mi * 16 + m16;
      const int kxa = (arow >> 2) & 7;
      bhalf8 afa[6];
      #pragma unroll
      for (int k = 0; k < 6; ++k)
        afa[k] = *reinterpret_cast<const bhalf8*>(sm.buf1 + arow * 200 + (((k * 4 + hb) ^ kxa) << 3));
      f32x4 accA[3];
      #pragma unroll
      for (int yt = 0; yt < 3; ++yt) {
        const int brow = (yb + yt) * 16 + m16;
        const int kxb = (brow >> 2) & 7;
        const short* Br = sm.buf2 + brow * 200;
        f32x4 acc = {0.f, 0.f, 0.f, 0.f};
        #pragma unroll
        for (int k = 0; k < 6; ++k) {
          bhalf8 bfy = *reinterpret_cast<const bhalf8*>(Br + (((k * 4 + hb) ^ kxb) << 3));
          acc = __builtin_amdgcn_mfma_f32_16x16x32_bf16(afa[k], bfy, acc, 0, 0, 0);
        }
        accA[yt] = acc;
      }
      __syncthreads();
      float* attf = reinterpret_cast<float*>(sm.buf1);
      const float scale = 0.07216878364870323f;   // 192^-0.5
      #pragma unroll
      for (int yt = 0; yt < 3; ++yt) {
        #pragma unroll
        for (int j = 0; j < 4; ++j) {
          int x = mi * 16 + r4 + j;
          int y = (yb + yt) * 16 + m16;
          attf[x * AS + (y ^ (x & 31))] = accA[yt][j] * scale;
        }
      }
    }
    __syncthreads();

    // phase 6: dual softmax -> P_row (bf16 [x][y], stride 104), P_colT ([y][x])
    {
      const float* attf = reinterpret_cast<const float*>(sm.buf1);
      short* Pr = sm.buf2;
      short* Pc = sm.buf2 + 96 * PS;
      const int r = tid >> 3;     // 0..95
      const int p = tid & 7;
      {   // row softmax (over y), r = x
        float av[12];
        #pragma unroll
        for (int k = 0; k < 12; ++k)
          av[k] = attf[r * AS + ((p * 12 + k) ^ (r & 31))];
        float mx = av[0];
        #pragma unroll
        for (int k = 1; k < 12; ++k) mx = fmaxf(mx, av[k]);
        mx = fmaxf(mx, __shfl_xor(mx, 1));
        mx = fmaxf(mx, __shfl_xor(mx, 2));
        mx = fmaxf(mx, __shfl_xor(mx, 4));
        float s = 0.f;
        #pragma unroll
        for (int k = 0; k < 12; ++k) { av[k] = __expf(av[k] - mx); s += av[k]; }
        s += __shfl_xor(s, 1); s += __shfl_xor(s, 2); s += __shfl_xor(s, 4);
        float inv = 1.f / s;
        #pragma unroll
        for (int k = 0; k < 12; k += 2) {
          unsigned u = (unsigned)f2bf(av[k] * inv) | ((unsigned)f2bf(av[k + 1] * inv) << 16);
          *reinterpret_cast<unsigned*>(Pr + r * PS + p * 12 + k) = u;
        }
      }
      {   // column softmax (over x), r = y; write transposed
        float av[12];
        #pragma unroll
        for (int k = 0; k < 12; ++k) {
          int x = p * 12 + k;
          av[k] = attf[x * AS + (r ^ (x & 31))];
        }
        float mx = av[0];
        #pragma unroll
        for (int k = 1; k < 12; ++k) mx = fmaxf(mx, av[k]);
        mx = fmaxf(mx, __shfl_xor(mx, 1));
        mx = fmaxf(mx, __shfl_xor(mx, 2));
        mx = fmaxf(mx, __shfl_xor(mx, 4));
        float s = 0.f;
        #pragma unroll
        for (int k = 0; k < 12; ++k) { av[k] = __expf(av[k] - mx); s += av[k]; }
        s += __shfl_xor(s, 1); s += __shfl_xor(s, 2); s += __shfl_xor(s, 4);
        float inv = 1.f / s;
        #pragma unroll
        for (int k = 0; k < 12; k += 2) {
          unsigned u = (unsigned)f2bf(av[k] * inv) | ((unsigned)f2bf(av[k + 1] * inv) << 16);
          *reinterpret_cast<unsigned*>(Pc + r * PS + p * 12 + k) = u;
        }
      }
    }
    __syncthreads();

    // phase 7: F_r2l = P_row * V_r, F_l2r = P_colT * V_l   (D[m=x|y][n=c])
    f32x4 accF[6], accG[6];
    {
      const short* Pr = sm.buf2;
      const short* Pc = sm.buf2 + 96 * PS;
      bhalf8 vf[3], vg[3];
      #pragma unroll
      for (int k = 0; k < 3; ++k) {
        vf[k] = *reinterpret_cast<const bhalf8*>(sm.vtr + o_wm * PS + k * 32 + kc8);
        vg[k] = *reinterpret_cast<const bhalf8*>(sm.vtl + o_wm * PS + k * 32 + kc8);
      }
      #pragma unroll
      for (int xi = 0; xi < 6; ++xi) {
        f32x4 a1 = {0.f, 0.f, 0.f, 0.f}, a2 = {0.f, 0.f, 0.f, 0.f};
        #pragma unroll
        for (int k = 0; k < 3; ++k) {
          bhalf8 ap = *reinterpret_cast<const bhalf8*>(Pr + (xi * 16 + m16) * PS + k * 32 + kc8);
          a1 = __builtin_amdgcn_mfma_f32_16x16x32_bf16(ap, vf[k], a1, 0, 0, 0);
          bhalf8 aq = *reinterpret_cast<const bhalf8*>(Pc + (xi * 16 + m16) * PS + k * 32 + kc8);
          a2 = __builtin_amdgcn_mfma_f32_16x16x32_bf16(aq, vg[k], a2, 0, 0, 0);
        }
        accF[xi] = a1; accG[xi] = a2;
      }
    }
    __syncthreads();
    {
      const int cc2 = o_wm;
      const int ob = cc2 & 7;
      #pragma unroll
      for (int xi = 0; xi < 6; ++xi) {
        const int kx = (4 * xi + hb) & 7;
        const int swo = ((((cc2 >> 3) ^ kx) << 3) | ob);
        #pragma unroll
        for (int j = 0; j < 4; ++j) {
          int x = xi * 16 + r4 + j;
          sm.buf1[x * 200 + swo] = (short)f2bf(accF[xi][j]);   // F_r2l [x][c]
          sm.buf2[x * 200 + swo] = (short)f2bf(accG[xi][j]);   // F_l2r [y][c]
        }
      }
    }
    __syncthreads();

    // phase 8: epilogue  out = x + F*coef + temb  (coalesced; x re-read L2/L3)
    #pragma unroll
    for (int sd = 0; sd < 2; ++sd) {
      const float* xg = sd ? x_r : x_l;
      float* og = out + (sd ? HALF_OUT : 0);
      const short* Fb = sd ? sm.buf2 : sm.buf1;
      const float* coef = sm.misc + (sd ? 768 : 576);
      #pragma unroll
      for (int j = 0; j < 6; ++j) {
        int i4 = j * 768 + tid;
        int c  = i4 / 24;
        int w4 = i4 - c * 24;
        const float4 xv = *reinterpret_cast<const float4*>(xg + sliceBase + c * HWc + w4 * 4);
        float cf = coef[c];
        float tv = sm.misc[384 + c];
        int sw = ((((c >> 3) ^ (w4 & 7)) << 3) | (c & 7));
        int fb = w4 * 800 + sw;
        float4 ov;
        ov.x = xv.x + bf2f_s(Fb[fb      ]) * cf + tv;
        ov.y = xv.y + bf2f_s(Fb[fb + 200]) * cf + tv;
        ov.z = xv.z + bf2f_s(Fb[fb + 400]) * cf + tv;
        ov.w = xv.w + bf2f_s(Fb[fb + 600]) * cf + tv;
        *reinterpret_cast<float4*>(og + sliceBase + c * HWc + w4 * 4) = ov;
      }
    }
    __syncthreads();   // protect buf1/buf2 overwrite at next loop head
  }
}

// -------------------------------------------------------------------- host ---
extern "C" void kernel_launch(void* const* d_in, const int* in_sizes, int n_in,
                              void* d_out, int out_size, void* d_ws, size_t ws_size,
                              hipStream_t stream)
{
  const float* t    = (const float*)d_in[0];
  const float* x_l  = (const float*)d_in[1];
  const float* x_r  = (const float*)d_in[2];
  const float* lnwl = (const float*)d_in[3];
  const float* lnbl = (const float*)d_in[4];
  const float* lnwr = (const float*)d_in[5];
  const float* lnbr = (const float*)d_in[6];
  const float* Wl1  = (const float*)d_in[7];
  const float* bl1  = (const float*)d_in[8];
  const float* Wr1  = (const float*)d_in[9];
  const float* br1  = (const float*)d_in[10];
  const float* Wl2  = (const float*)d_in[11];
  const float* bl2  = (const float*)d_in[12];
  const float* Wr2  = (const float*)d_in[13];
  const float* br2  = (const float*)d_in[14];
  const float* beta = (const float*)d_in[15];
  const float* gamma= (const float*)d_in[16];
  const float* Wt   = (const float*)d_in[17];
  const float* bt   = (const float*)d_in[18];
  float* out = (float*)d_out;

  char* ws = (char*)d_ws;
  short* W1l_b = (short*)ws;
  short* W1r_b = W1l_b + 36864;
  short* W2l_b = W1r_b + 36864;
  short* W2r_b = W2l_b + 36864;
  float* fws  = (float*)(ws + 4 * 73728);
  float* s1l  = fws;
  float* t1l  = fws + 192;
  float* s1r  = fws + 384;
  float* t1r  = fws + 576;
  float* temb = fws + 768;   // 3072 floats
  float* mt   = fws + 3840;  // 8192 floats

  setup1<<<610, 256, 0, stream>>>(t, lnwl, lnbl, lnwr, lnbr, Wl1, bl1, Wr1, br1,
                                  Wl2, Wr2, W1l_b, W1r_b, W2l_b, W2r_b,
                                  s1l, t1l, s1r, t1r, mt);
  setup2<<<12, 256, 0, stream>>>(mt, Wt, bt, temb);
  scam_main<<<256, 768, 0, stream>>>(x_l, x_r, bl2, br2, beta, gamma,
                                     W1l_b, W1r_b, W2l_b, W2r_b,
                                     s1l, t1l, s1r, t1r, temb, out);
}

// Round 5
// 369.352 us; speedup vs baseline: 2.2426x; 2.2426x over previous
//
#include <hip/hip_runtime.h>

// SCAM fused kernel for MI355X (gfx950).
// One workgroup per (b,h) attention slice; everything (LN, 4 projections,
// QK^T, dual softmax, 2x PV, epilogue) stays in LDS.
// R5: R3 structure (1536 WGs, no persistence). Epilogue x re-read eliminated:
// staging keeps each thread's 48 x-values as packed bf16 in 24 VGPRs, and the
// epilogue reconstructs the residual from registers (no global reads at all).

typedef __attribute__((ext_vector_type(8))) short bhalf8;   // 8 bf16 in 4 VGPRs
typedef __attribute__((ext_vector_type(4))) float f32x4;

#define DEVI static __device__ __forceinline__

constexpr int Cc   = 192;
constexpr int HWc  = 9216;          // 96*96
constexpr int CHW  = 192 * 9216;    // per-batch image
constexpr int HALF_OUT = 16 * CHW;  // 28311552
constexpr int PS   = 104;           // padded row stride (halves) for P and Vt
constexpr int AS   = 100;           // att row stride (dwords)

DEVI unsigned short f2bf(float f) {           // round-to-nearest-even fp32->bf16
  unsigned u = __builtin_bit_cast(unsigned, f);
  u += 0x7fffu + ((u >> 16) & 1u);
  return (unsigned short)(u >> 16);
}
DEVI float bf2f(unsigned short h) {
  unsigned u = (unsigned)h << 16;
  return __builtin_bit_cast(float, u);
}
DEVI float bf2f_s(short h) { return bf2f((unsigned short)h); }

// ---------------------------------------------------------------- setup 1 ---
__global__ void setup1(
    const float* __restrict__ t,
    const float* __restrict__ lnwl, const float* __restrict__ lnbl,
    const float* __restrict__ lnwr, const float* __restrict__ lnbr,
    const float* __restrict__ Wl1, const float* __restrict__ bl1,
    const float* __restrict__ Wr1, const float* __restrict__ br1,
    const float* __restrict__ Wl2, const float* __restrict__ Wr2,
    short* __restrict__ W1l_b, short* __restrict__ W1r_b,
    short* __restrict__ W2l_b, short* __restrict__ W2r_b,
    float* __restrict__ s1l, float* __restrict__ t1l,
    float* __restrict__ s1r, float* __restrict__ t1r,
    float* __restrict__ mt)
{
  const int blk = blockIdx.x, tid = threadIdx.x;
  if (blk < 576) {
    int id  = blk * 256 + tid;          // < 147456
    int m   = id / 36864;
    int rem = id - m * 36864;
    int c   = rem % 192;
    float v;
    short* dst;
    if (m == 0)      { v = lnwl[c] * Wl1[rem]; dst = W1l_b; }
    else if (m == 1) { v = lnwr[c] * Wr1[rem]; dst = W1r_b; }
    else if (m == 2) { v = Wl2[rem];           dst = W2l_b; }
    else             { v = Wr2[rem];           dst = W2r_b; }
    dst[rem] = (short)f2bf(v);
  } else if (blk == 576 || blk == 577) {
    if (tid < 192) {
      const float* Wm = (blk == 576) ? Wl1 : Wr1;
      const float* lw = (blk == 576) ? lnwl : lnwr;
      const float* lb = (blk == 576) ? lnbl : lnbr;
      const float* bb = (blk == 576) ? bl1 : br1;
      float s = 0.f, tb = 0.f;
      for (int c = 0; c < 192; ++c) {
        float wv = Wm[tid * 192 + c];
        s  += lw[c] * wv;
        tb += lb[c] * wv;
      }
      if (blk == 576) { s1l[tid] = s; t1l[tid] = tb + bb[tid]; }
      else            { s1r[tid] = s; t1r[tid] = tb + bb[tid]; }
    }
  } else {
    int id = (blk - 578) * 256 + tid;   // < 8192
    float v = t[id];
    float sp = (v > 20.f) ? v : log1pf(__expf(v));
    mt[id] = v * tanhf(sp);
  }
}

// temb[b][o] = sum_k mish(t)[b][k] * Wt[o][k] + bt[o]
__global__ void setup2(const float* __restrict__ mt, const float* __restrict__ Wt,
                       const float* __restrict__ bt, float* __restrict__ temb)
{
  int id = blockIdx.x * 256 + threadIdx.x;  // < 3072
  int b = id / 192, o = id - b * 192;
  float s = 0.f;
  for (int k = 0; k < 512; ++k) s += mt[b * 512 + k] * Wt[o * 512 + k];
  temb[id] = s + bt[o];
}

// ------------------------------------------------------------- main kernel ---
// misc layout (floats): 0 mu_l[96], 96 rs_l[96], 192 mu_r[96], 288 rs_r[96],
// 384 te[192], 576 beta[192], 768 gamma[192]   (end 960)
struct SmemT {
  short buf1[96 * 200];   // XT_l -> Q_l -> att(fp32, stride 100dw) -> F_r2l 38400 B
  short buf2[19968];      // XT_r -> Q_r -> P_row/P_colT -> F_l2r            39936 B
  short vtl[192 * PS];    // V_l^T [c][x] stride 104                         39936 B
  short vtr[192 * PS];    // V_r^T [c][y] stride 104                         39936 B
  float misc[960];        //                                                  3840 B
};
static_assert(sizeof(SmemT) <= 163840, "LDS overflow");

__launch_bounds__(768, 3)
__global__ void scam_main(
    const float* __restrict__ x_l, const float* __restrict__ x_r,
    const float* __restrict__ bl2, const float* __restrict__ br2,
    const float* __restrict__ beta, const float* __restrict__ gamma,
    const short* __restrict__ W1l_b, const short* __restrict__ W1r_b,
    const short* __restrict__ W2l_b, const short* __restrict__ W2r_b,
    const float* __restrict__ s1l, const float* __restrict__ t1l,
    const float* __restrict__ s1r, const float* __restrict__ t1r,
    const float* __restrict__ temb,
    float* __restrict__ out)
{
  __shared__ SmemT sm;
  const int tid  = threadIdx.x;
  const int lane = tid & 63;
  const int wid  = tid >> 6;            // 0..11
  const int m16  = lane & 15;
  const int hb   = lane >> 4;           // 0..3
  const int kc8  = hb * 8;              // element offset within a fragment row
  const int r4   = hb * 4;              // D-row base
  const int slice = blockIdx.x;
  const int bb_ = slice / 96;
  const int hh_ = slice - bb_ * 96;
  const int sliceBase = bb_ * CHW + hh_ * 96;
  const int o_wm = wid * 16 + m16;

  // per-lane parameter registers (L2-hot scalar loads, issued once)
  float s1Lr = s1l[o_wm], t1Lr = t1l[o_wm];
  float s1Rr = s1r[o_wm], t1Rr = t1r[o_wm];
  float bvL[4], bvR[4];
  #pragma unroll
  for (int j = 0; j < 4; ++j) {
    bvL[j] = bl2[wid * 16 + r4 + j];
    bvR[j] = br2[wid * 16 + r4 + j];
  }

  // phase 0: small vectors into LDS (te, beta, gamma)
  if (tid < 576) {
    int a = tid / 192, o = tid - a * 192;
    if (a == 0)      sm.misc[384 + o] = temb[bb_ * 192 + o];
    else if (a == 1) sm.misc[576 + o] = beta[o];
    else             sm.misc[768 + o] = gamma[o];
  }

  // phase 1: stage x -> bf16 [w][c] rows (stride 200), coalesced global reads,
  // block-XOR LDS swizzle: element (w,c) at w*200 + ((c>>3)^((w>>2)&7))*8 + (c&7).
  // Each thread ALSO keeps its 48 bf16 x-values packed in 24 VGPRs for the
  // epilogue residual (statically-indexed, fully-unrolled -> no scratch).
  unsigned xlr[12], xrr[12];
  #pragma unroll
  for (int j = 0; j < 6; ++j) {
    int i4 = j * 768 + tid;             // < 4608
    int c  = i4 / 24;
    int w4 = i4 - c * 24;               // w = 4*w4 + r, (w>>2)&7 = w4&7
    const float4 xl4 = *reinterpret_cast<const float4*>(x_l + sliceBase + c * HWc + w4 * 4);
    const float4 xr4 = *reinterpret_cast<const float4*>(x_r + sliceBase + c * HWc + w4 * 4);
    unsigned short lx = f2bf(xl4.x), ly = f2bf(xl4.y), lz = f2bf(xl4.z), lw = f2bf(xl4.w);
    unsigned short rx = f2bf(xr4.x), ry = f2bf(xr4.y), rz = f2bf(xr4.z), rw = f2bf(xr4.w);
    xlr[2 * j]     = (unsigned)lx | ((unsigned)ly << 16);
    xlr[2 * j + 1] = (unsigned)lz | ((unsigned)lw << 16);
    xrr[2 * j]     = (unsigned)rx | ((unsigned)ry << 16);
    xrr[2 * j + 1] = (unsigned)rz | ((unsigned)rw << 16);
    int sw = ((((c >> 3) ^ (w4 & 7)) << 3) | (c & 7));
    int base = w4 * 800 + sw;
    sm.buf1[base      ] = (short)lx;
    sm.buf1[base + 200] = (short)ly;
    sm.buf1[base + 400] = (short)lz;
    sm.buf1[base + 600] = (short)lw;
    sm.buf2[base      ] = (short)rx;
    sm.buf2[base + 200] = (short)ry;
    sm.buf2[base + 400] = (short)rz;
    sm.buf2[base + 600] = (short)rw;
  }

  // prefetch W1 fragments (used in phase 4); latency hides under phases 2-3
  bhalf8 bfqL[6], bfqR[6];
  #pragma unroll
  for (int k = 0; k < 6; ++k) {
    bfqL[k] = *reinterpret_cast<const bhalf8*>(W1l_b + o_wm * 192 + k * 32 + kc8);
    bfqR[k] = *reinterpret_cast<const bhalf8*>(W1r_b + o_wm * 192 + k * 32 + kc8);
  }
  __syncthreads();

  // phase 2: LN stats per pixel (reads swizzled blocks; sum order irrelevant)
  {
    int side = (tid >= 384) ? 1 : 0;
    int rest = tid - side * 384;
    int w = rest >> 2;
    int q = rest & 3;
    const short* Xb = side ? sm.buf2 : sm.buf1;
    const int kxw = (w >> 2) & 7;
    float s0 = 0.f, s2 = 0.f;
    #pragma unroll
    for (int mc = 0; mc < 6; ++mc) {
      bhalf8 v = *reinterpret_cast<const bhalf8*>(Xb + w * 200 + (((q * 6 + mc) ^ kxw) << 3));
      #pragma unroll
      for (int e = 0; e < 8; ++e) { float f = bf2f_s(v[e]); s0 += f; s2 += f * f; }
    }
    s0 += __shfl_xor(s0, 1); s2 += __shfl_xor(s2, 1);
    s0 += __shfl_xor(s0, 2); s2 += __shfl_xor(s2, 2);
    if (q == 0) {
      float mu  = s0 * (1.f / 192.f);
      float var = s2 * (1.f / 192.f) - mu * mu;
      float rs  = rsqrtf(var + 1e-6f);
      sm.misc[side * 192 + w]      = mu;
      sm.misc[side * 192 + 96 + w] = rs;
    }
  }

  // phase 3: V^T = W2 * X^T  -> vtl/vtr (stride 104)   (D[m=c][n=x])
  #pragma unroll
  for (int sd = 0; sd < 2; ++sd) {
    const short* Wb = sd ? W2r_b : W2l_b;
    const short* Xb = sd ? sm.buf2 : sm.buf1;
    short* Vt = sd ? sm.vtr : sm.vtl;
    const float* bv = sd ? bvR : bvL;
    bhalf8 af[6];
    #pragma unroll
    for (int k = 0; k < 6; ++k)
      af[k] = *reinterpret_cast<const bhalf8*>(Wb + o_wm * 192 + k * 32 + kc8);
    #pragma unroll
    for (int xi = 0; xi < 6; ++xi) {
      const int row = xi * 16 + m16;
      const int kxr = (row >> 2) & 7;
      const short* Xr = Xb + row * 200;
      f32x4 acc = {0.f, 0.f, 0.f, 0.f};
      #pragma unroll
      for (int k = 0; k < 6; ++k) {
        bhalf8 bfr = *reinterpret_cast<const bhalf8*>(Xr + (((k * 4 + hb) ^ kxr) << 3));
        acc = __builtin_amdgcn_mfma_f32_16x16x32_bf16(af[k], bfr, acc, 0, 0, 0);
      }
      const int xcol = xi * 16 + m16;
      #pragma unroll
      for (int j = 0; j < 4; ++j) {
        int cr = wid * 16 + r4 + j;
        Vt[cr * PS + xcol] = (short)f2bf(acc[j] + bv[j]);
      }
    }
  }

  // phase 4: Q projections into registers (D[m=x][n=o])
  f32x4 accQ0[6], accQ1[6];
  {
    #pragma unroll
    for (int mi = 0; mi < 6; ++mi) {
      const int row = mi * 16 + m16;
      const int kxr = (row >> 2) & 7;
      const short* Xr = sm.buf1 + row * 200;
      f32x4 acc = {0.f, 0.f, 0.f, 0.f};
      #pragma unroll
      for (int k = 0; k < 6; ++k) {
        bhalf8 afr = *reinterpret_cast<const bhalf8*>(Xr + (((k * 4 + hb) ^ kxr) << 3));
        acc = __builtin_amdgcn_mfma_f32_16x16x32_bf16(afr, bfqL[k], acc, 0, 0, 0);
      }
      accQ0[mi] = acc;
    }
    #pragma unroll
    for (int mi = 0; mi < 6; ++mi) {
      const int row = mi * 16 + m16;
      const int kxr = (row >> 2) & 7;
      const short* Xr = sm.buf2 + row * 200;
      f32x4 acc = {0.f, 0.f, 0.f, 0.f};
      #pragma unroll
      for (int k = 0; k < 6; ++k) {
        bhalf8 afr = *reinterpret_cast<const bhalf8*>(Xr + (((k * 4 + hb) ^ kxr) << 3));
        acc = __builtin_amdgcn_mfma_f32_16x16x32_bf16(afr, bfqR[k], acc, 0, 0, 0);
      }
      accQ1[mi] = acc;
    }
  }
  __syncthreads();
  // write Q with folded LayerNorm affine: Q = rs*acc - mu*rs*s1[o] + t1[o]
  {
    const int o = o_wm;
    const int ob = o & 7;
    #pragma unroll
    for (int sd = 0; sd < 2; ++sd) {
      short* Qb = sd ? sm.buf2 : sm.buf1;
      const float* muA = sm.misc + sd * 192;
      const float* rsA = muA + 96;
      float s1o = sd ? s1Rr : s1Lr;
      float t1o = sd ? t1Rr : t1Lr;
      #pragma unroll
      for (int mi = 0; mi < 6; ++mi) {
        const int kx = (4 * mi + hb) & 7;        // (x>>2)&7 for x = mi*16+r4+j
        const int swo = (((o >> 3) ^ kx) << 3) | ob;
        f32x4 acc = sd ? accQ1[mi] : accQ0[mi];
        #pragma unroll
        for (int j = 0; j < 4; ++j) {
          int x = mi * 16 + r4 + j;
          float mu = muA[x], rs = rsA[x];
          Qb[x * 200 + swo] = (short)f2bf(rs * acc[j] - mu * rs * s1o + t1o);
        }
      }
    }
  }
  __syncthreads();

  // phase 5: att = Q_l * Q_r^T (scaled) -> fp32 over buf1, stride 100 dwords,
  // column swizzle y ^ (x&31)
  {
    const int mi = wid >> 1;
    const int yb = (wid & 1) * 3;
    const int arow = mi * 16 + m16;
    const int kxa = (arow >> 2) & 7;
    bhalf8 afa[6];
    #pragma unroll
    for (int k = 0; k < 6; ++k)
      afa[k] = *reinterpret_cast<const bhalf8*>(sm.buf1 + arow * 200 + (((k * 4 + hb) ^ kxa) << 3));
    f32x4 accA[3];
    #pragma unroll
    for (int yt = 0; yt < 3; ++yt) {
      const int brow = (yb + yt) * 16 + m16;
      const int kxb = (brow >> 2) & 7;
      const short* Br = sm.buf2 + brow * 200;
      f32x4 acc = {0.f, 0.f, 0.f, 0.f};
      #pragma unroll
      for (int k = 0; k < 6; ++k) {
        bhalf8 bfy = *reinterpret_cast<const bhalf8*>(Br + (((k * 4 + hb) ^ kxb) << 3));
        acc = __builtin_amdgcn_mfma_f32_16x16x32_bf16(afa[k], bfy, acc, 0, 0, 0);
      }
      accA[yt] = acc;
    }
    __syncthreads();
    float* attf = reinterpret_cast<float*>(sm.buf1);
    const float scale = 0.07216878364870323f;   // 192^-0.5
    #pragma unroll
    for (int yt = 0; yt < 3; ++yt) {
      #pragma unroll
      for (int j = 0; j < 4; ++j) {
        int x = mi * 16 + r4 + j;
        int y = (yb + yt) * 16 + m16;
        attf[x * AS + (y ^ (x & 31))] = accA[yt][j] * scale;
      }
    }
  }
  __syncthreads();

  // phase 6: dual softmax -> P_row (bf16 [x][y], stride 104) and P_colT ([y][x])
  {
    const float* attf = reinterpret_cast<const float*>(sm.buf1);
    short* Pr = sm.buf2;
    short* Pc = sm.buf2 + 96 * PS;
    const int r = tid >> 3;     // 0..95
    const int p = tid & 7;
    {   // row softmax (over y), r = x
      float av[12];
      #pragma unroll
      for (int k = 0; k < 12; ++k)
        av[k] = attf[r * AS + ((p * 12 + k) ^ (r & 31))];
      float mx = av[0];
      #pragma unroll
      for (int k = 1; k < 12; ++k) mx = fmaxf(mx, av[k]);
      mx = fmaxf(mx, __shfl_xor(mx, 1));
      mx = fmaxf(mx, __shfl_xor(mx, 2));
      mx = fmaxf(mx, __shfl_xor(mx, 4));
      float s = 0.f;
      #pragma unroll
      for (int k = 0; k < 12; ++k) { av[k] = __expf(av[k] - mx); s += av[k]; }
      s += __shfl_xor(s, 1); s += __shfl_xor(s, 2); s += __shfl_xor(s, 4);
      float inv = 1.f / s;
      #pragma unroll
      for (int k = 0; k < 12; k += 2) {
        unsigned u = (unsigned)f2bf(av[k] * inv) | ((unsigned)f2bf(av[k + 1] * inv) << 16);
        *reinterpret_cast<unsigned*>(Pr + r * PS + p * 12 + k) = u;
      }
    }
    {   // column softmax (over x), r = y; write transposed
      float av[12];
      #pragma unroll
      for (int k = 0; k < 12; ++k) {
        int x = p * 12 + k;
        av[k] = attf[x * AS + (r ^ (x & 31))];
      }
      float mx = av[0];
      #pragma unroll
      for (int k = 1; k < 12; ++k) mx = fmaxf(mx, av[k]);
      mx = fmaxf(mx, __shfl_xor(mx, 1));
      mx = fmaxf(mx, __shfl_xor(mx, 2));
      mx = fmaxf(mx, __shfl_xor(mx, 4));
      float s = 0.f;
      #pragma unroll
      for (int k = 0; k < 12; ++k) { av[k] = __expf(av[k] - mx); s += av[k]; }
      s += __shfl_xor(s, 1); s += __shfl_xor(s, 2); s += __shfl_xor(s, 4);
      float inv = 1.f / s;
      #pragma unroll
      for (int k = 0; k < 12; k += 2) {
        unsigned u = (unsigned)f2bf(av[k] * inv) | ((unsigned)f2bf(av[k + 1] * inv) << 16);
        *reinterpret_cast<unsigned*>(Pc + r * PS + p * 12 + k) = u;
      }
    }
  }
  __syncthreads();

  // phase 7: F_r2l = P_row * V_r, F_l2r = P_colT * V_l   (D[m=x|y][n=c])
  f32x4 accF[6], accG[6];
  {
    const short* Pr = sm.buf2;
    const short* Pc = sm.buf2 + 96 * PS;
    bhalf8 vf[3], vg[3];
    #pragma unroll
    for (int k = 0; k < 3; ++k) {
      vf[k] = *reinterpret_cast<const bhalf8*>(sm.vtr + o_wm * PS + k * 32 + kc8);
      vg[k] = *reinterpret_cast<const bhalf8*>(sm.vtl + o_wm * PS + k * 32 + kc8);
    }
    #pragma unroll
    for (int xi = 0; xi < 6; ++xi) {
      f32x4 a1 = {0.f, 0.f, 0.f, 0.f}, a2 = {0.f, 0.f, 0.f, 0.f};
      #pragma unroll
      for (int k = 0; k < 3; ++k) {
        bhalf8 ap = *reinterpret_cast<const bhalf8*>(Pr + (xi * 16 + m16) * PS + k * 32 + kc8);
        a1 = __builtin_amdgcn_mfma_f32_16x16x32_bf16(ap, vf[k], a1, 0, 0, 0);
        bhalf8 aq = *reinterpret_cast<const bhalf8*>(Pc + (xi * 16 + m16) * PS + k * 32 + kc8);
        a2 = __builtin_amdgcn_mfma_f32_16x16x32_bf16(aq, vg[k], a2, 0, 0, 0);
      }
      accF[xi] = a1; accG[xi] = a2;
    }
  }
  __syncthreads();
  {
    const int cc2 = o_wm;
    const int ob = cc2 & 7;
    #pragma unroll
    for (int xi = 0; xi < 6; ++xi) {
      const int kx = (4 * xi + hb) & 7;
      const int swo = ((((cc2 >> 3) ^ kx) << 3) | ob);
      #pragma unroll
      for (int j = 0; j < 4; ++j) {
        int x = xi * 16 + r4 + j;
        sm.buf1[x * 200 + swo] = (short)f2bf(accF[xi][j]);   // F_r2l [x][c]
        sm.buf2[x * 200 + swo] = (short)f2bf(accG[xi][j]);   // F_l2r [y][c]
      }
    }
  }
  __syncthreads();

  // phase 8: epilogue  out = bf16(x) + F*coef + temb
  // x comes from the packed register copies kept since staging (same thread ->
  // same (c,w4) mapping). NO global reads in this phase; stores fully coalesced.
  #pragma unroll
  for (int sd = 0; sd < 2; ++sd) {
    float* og = out + (sd ? HALF_OUT : 0);
    const short* Fb = sd ? sm.buf2 : sm.buf1;
    const unsigned* xp = sd ? xrr : xlr;
    const float* coef = sm.misc + (sd ? 768 : 576);
    #pragma unroll
    for (int j = 0; j < 6; ++j) {
      int i4 = j * 768 + tid;
      int c  = i4 / 24;
      int w4 = i4 - c * 24;
      unsigned plo = xp[2 * j], phi = xp[2 * j + 1];
      float cf = coef[c];
      float tv = sm.misc[384 + c];
      int sw = ((((c >> 3) ^ (w4 & 7)) << 3) | (c & 7));
      int fb = w4 * 800 + sw;
      float4 ov;
      ov.x = bf2f((unsigned short)(plo & 0xffffu)) + bf2f_s(Fb[fb      ]) * cf + tv;
      ov.y = bf2f((unsigned short)(plo >> 16))     + bf2f_s(Fb[fb + 200]) * cf + tv;
      ov.z = bf2f((unsigned short)(phi & 0xffffu)) + bf2f_s(Fb[fb + 400]) * cf + tv;
      ov.w = bf2f((unsigned short)(phi >> 16))     + bf2f_s(Fb[fb + 600]) * cf + tv;
      *reinterpret_cast<float4*>(og + sliceBase + c * HWc + w4 * 4) = ov;
    }
  }
}

// -------------------------------------------------------------------- host ---
extern "C" void kernel_launch(void* const* d_in, const int* in_sizes, int n_in,
                              void* d_out, int out_size, void* d_ws, size_t ws_size,
                              hipStream_t stream)
{
  const float* t    = (const float*)d_in[0];
  const float* x_l  = (const float*)d_in[1];
  const float* x_r  = (const float*)d_in[2];
  const float* lnwl = (const float*)d_in[3];
  const float* lnbl = (const float*)d_in[4];
  const float* lnwr = (const float*)d_in[5];
  const float* lnbr = (const float*)d_in[6];
  const float* Wl1  = (const float*)d_in[7];
  const float* bl1  = (const float*)d_in[8];
  const float* Wr1  = (const float*)d_in[9];
  const float* br1  = (const float*)d_in[10];
  const float* Wl2  = (const float*)d_in[11];
  const float* bl2  = (const float*)d_in[12];
  const float* Wr2  = (const float*)d_in[13];
  const float* br2  = (const float*)d_in[14];
  const float* beta = (const float*)d_in[15];
  const float* gamma= (const float*)d_in[16];
  const float* Wt   = (const float*)d_in[17];
  const float* bt   = (const float*)d_in[18];
  float* out = (float*)d_out;

  char* ws = (char*)d_ws;
  short* W1l_b = (short*)ws;
  short* W1r_b = W1l_b + 36864;
  short* W2l_b = W1r_b + 36864;
  short* W2r_b = W2l_b + 36864;
  float* fws  = (float*)(ws + 4 * 73728);
  float* s1l  = fws;
  float* t1l  = fws + 192;
  float* s1r  = fws + 384;
  float* t1r  = fws + 576;
  float* temb = fws + 768;   // 3072 floats
  float* mt   = fws + 3840;  // 8192 floats

  setup1<<<610, 256, 0, stream>>>(t, lnwl, lnbl, lnwr, lnbr, Wl1, bl1, Wr1, br1,
                                  Wl2, Wr2, W1l_b, W1r_b, W2l_b, W2r_b,
                                  s1l, t1l, s1r, t1r, mt);
  setup2<<<12, 256, 0, stream>>>(mt, Wt, bt, temb);
  scam_main<<<1536, 768, 0, stream>>>(x_l, x_r, bl2, br2, beta, gamma,
                                      W1l_b, W1r_b, W2l_b, W2r_b,
                                      s1l, t1l, s1r, t1r, temb, out);
}

// Round 6
// 263.473 us; speedup vs baseline: 3.1438x; 1.4019x over previous
//
#include <hip/hip_runtime.h>

// SCAM fused kernel for MI355X (gfx950).
// One workgroup per (b,h) attention slice; everything (LN, 4 projections,
// QK^T, dual softmax, 2x PV, epilogue) stays in LDS.
// R6 = R1's register discipline + R3's LDS swizzles.
//   - NO register arrays held across phases (unified VGPR/AGPR budget is
//     cap-pinned at ~170 for 3 waves/SIMD; holds spill to scratch = HBM).
//   - Params (s1/t1/bv) loaded transiently from L2-hot global inside phases.
//   - W1 fragments loaded inside phase 4 (scoped), not hoisted.
//   - Block-XOR swizzle on [w][c] buffers, att stride 100 dw, P/Vt stride 104.

typedef __attribute__((ext_vector_type(8))) short bhalf8;   // 8 bf16 in 4 VGPRs
typedef __attribute__((ext_vector_type(4))) float f32x4;

#define DEVI static __device__ __forceinline__

constexpr int Cc   = 192;
constexpr int HWc  = 9216;          // 96*96
constexpr int CHW  = 192 * 9216;    // per-batch image
constexpr int HALF_OUT = 16 * CHW;  // 28311552
constexpr int PS   = 104;           // padded row stride (halves) for P and Vt
constexpr int AS   = 100;           // att row stride (dwords)

DEVI unsigned short f2bf(float f) {           // round-to-nearest-even fp32->bf16
  unsigned u = __builtin_bit_cast(unsigned, f);
  u += 0x7fffu + ((u >> 16) & 1u);
  return (unsigned short)(u >> 16);
}
DEVI float bf2f(unsigned short h) {
  unsigned u = (unsigned)h << 16;
  return __builtin_bit_cast(float, u);
}
DEVI float bf2f_s(short h) { return bf2f((unsigned short)h); }

// ---------------------------------------------------------------- setup 1 ---
__global__ void setup1(
    const float* __restrict__ t,
    const float* __restrict__ lnwl, const float* __restrict__ lnbl,
    const float* __restrict__ lnwr, const float* __restrict__ lnbr,
    const float* __restrict__ Wl1, const float* __restrict__ bl1,
    const float* __restrict__ Wr1, const float* __restrict__ br1,
    const float* __restrict__ Wl2, const float* __restrict__ Wr2,
    short* __restrict__ W1l_b, short* __restrict__ W1r_b,
    short* __restrict__ W2l_b, short* __restrict__ W2r_b,
    float* __restrict__ s1l, float* __restrict__ t1l,
    float* __restrict__ s1r, float* __restrict__ t1r,
    float* __restrict__ mt)
{
  const int blk = blockIdx.x, tid = threadIdx.x;
  if (blk < 576) {
    int id  = blk * 256 + tid;          // < 147456
    int m   = id / 36864;
    int rem = id - m * 36864;
    int c   = rem % 192;
    float v;
    short* dst;
    if (m == 0)      { v = lnwl[c] * Wl1[rem]; dst = W1l_b; }
    else if (m == 1) { v = lnwr[c] * Wr1[rem]; dst = W1r_b; }
    else if (m == 2) { v = Wl2[rem];           dst = W2l_b; }
    else             { v = Wr2[rem];           dst = W2r_b; }
    dst[rem] = (short)f2bf(v);
  } else if (blk == 576 || blk == 577) {
    if (tid < 192) {
      const float* Wm = (blk == 576) ? Wl1 : Wr1;
      const float* lw = (blk == 576) ? lnwl : lnwr;
      const float* lb = (blk == 576) ? lnbl : lnbr;
      const float* bb = (blk == 576) ? bl1 : br1;
      float s = 0.f, tb = 0.f;
      for (int c = 0; c < 192; ++c) {
        float wv = Wm[tid * 192 + c];
        s  += lw[c] * wv;
        tb += lb[c] * wv;
      }
      if (blk == 576) { s1l[tid] = s; t1l[tid] = tb + bb[tid]; }
      else            { s1r[tid] = s; t1r[tid] = tb + bb[tid]; }
    }
  } else {
    int id = (blk - 578) * 256 + tid;   // < 8192
    float v = t[id];
    float sp = (v > 20.f) ? v : log1pf(__expf(v));
    mt[id] = v * tanhf(sp);
  }
}

// temb[b][o] = sum_k mish(t)[b][k] * Wt[o][k] + bt[o]
__global__ void setup2(const float* __restrict__ mt, const float* __restrict__ Wt,
                       const float* __restrict__ bt, float* __restrict__ temb)
{
  int id = blockIdx.x * 256 + threadIdx.x;  // < 3072
  int b = id / 192, o = id - b * 192;
  float s = 0.f;
  for (int k = 0; k < 512; ++k) s += mt[b * 512 + k] * Wt[o * 512 + k];
  temb[id] = s + bt[o];
}

// ------------------------------------------------------------- main kernel ---
// misc layout (floats): 0 mu_l[96], 96 rs_l[96], 192 mu_r[96], 288 rs_r[96],
// 384 te[192], 576 beta[192], 768 gamma[192]   (end 960)
struct SmemT {
  short buf1[96 * 200];   // XT_l -> Q_l -> att(fp32, stride 100dw) -> F_r2l 38400 B
  short buf2[19968];      // XT_r -> Q_r -> P_row/P_colT -> F_l2r            39936 B
  short vtl[192 * PS];    // V_l^T [c][x] stride 104                         39936 B
  short vtr[192 * PS];    // V_r^T [c][y] stride 104                         39936 B
  float misc[960];        //                                                  3840 B
};
static_assert(sizeof(SmemT) <= 163840, "LDS overflow");

__launch_bounds__(768, 3)
__global__ void scam_main(
    const float* __restrict__ x_l, const float* __restrict__ x_r,
    const float* __restrict__ bl2, const float* __restrict__ br2,
    const float* __restrict__ beta, const float* __restrict__ gamma,
    const short* __restrict__ W1l_b, const short* __restrict__ W1r_b,
    const short* __restrict__ W2l_b, const short* __restrict__ W2r_b,
    const float* __restrict__ s1l, const float* __restrict__ t1l,
    const float* __restrict__ s1r, const float* __restrict__ t1r,
    const float* __restrict__ temb,
    float* __restrict__ out)
{
  __shared__ SmemT sm;
  const int tid  = threadIdx.x;
  const int lane = tid & 63;
  const int wid  = tid >> 6;            // 0..11
  const int m16  = lane & 15;
  const int hb   = lane >> 4;           // 0..3
  const int kc8  = hb * 8;              // element offset within a fragment row
  const int r4   = hb * 4;              // D-row base
  const int slice = blockIdx.x;
  const int bb_ = slice / 96;
  const int hh_ = slice - bb_ * 96;
  const int sliceBase = bb_ * CHW + hh_ * 96;
  const int o_wm = wid * 16 + m16;

  // phase 0: small vectors into LDS (te, beta, gamma)
  if (tid < 576) {
    int a = tid / 192, o = tid - a * 192;
    if (a == 0)      sm.misc[384 + o] = temb[bb_ * 192 + o];
    else if (a == 1) sm.misc[576 + o] = beta[o];
    else             sm.misc[768 + o] = gamma[o];
  }

  // phase 1: stage x -> bf16 [w][c] rows (stride 200), coalesced global reads,
  // block-XOR LDS swizzle: element (w,c) at w*200 + ((c>>3)^((w>>2)&7))*8 + (c&7)
  #pragma unroll
  for (int j = 0; j < 6; ++j) {
    int i4 = j * 768 + tid;             // < 4608
    int c  = i4 / 24;
    int w4 = i4 - c * 24;               // w = 4*w4 + r, (w>>2)&7 = w4&7
    const float4 xl4 = *reinterpret_cast<const float4*>(x_l + sliceBase + c * HWc + w4 * 4);
    const float4 xr4 = *reinterpret_cast<const float4*>(x_r + sliceBase + c * HWc + w4 * 4);
    int sw = ((((c >> 3) ^ (w4 & 7)) << 3) | (c & 7));
    int base = w4 * 800 + sw;
    sm.buf1[base      ] = (short)f2bf(xl4.x);
    sm.buf1[base + 200] = (short)f2bf(xl4.y);
    sm.buf1[base + 400] = (short)f2bf(xl4.z);
    sm.buf1[base + 600] = (short)f2bf(xl4.w);
    sm.buf2[base      ] = (short)f2bf(xr4.x);
    sm.buf2[base + 200] = (short)f2bf(xr4.y);
    sm.buf2[base + 400] = (short)f2bf(xr4.z);
    sm.buf2[base + 600] = (short)f2bf(xr4.w);
  }
  __syncthreads();

  // phase 2: LN stats per pixel (reads swizzled blocks; sum order irrelevant)
  {
    int side = (tid >= 384) ? 1 : 0;
    int rest = tid - side * 384;
    int w = rest >> 2;
    int q = rest & 3;
    const short* Xb = side ? sm.buf2 : sm.buf1;
    const int kxw = (w >> 2) & 7;
    float s0 = 0.f, s2 = 0.f;
    #pragma unroll
    for (int mc = 0; mc < 6; ++mc) {
      bhalf8 v = *reinterpret_cast<const bhalf8*>(Xb + w * 200 + (((q * 6 + mc) ^ kxw) << 3));
      #pragma unroll
      for (int e = 0; e < 8; ++e) { float f = bf2f_s(v[e]); s0 += f; s2 += f * f; }
    }
    s0 += __shfl_xor(s0, 1); s2 += __shfl_xor(s2, 1);
    s0 += __shfl_xor(s0, 2); s2 += __shfl_xor(s2, 2);
    if (q == 0) {
      float mu  = s0 * (1.f / 192.f);
      float var = s2 * (1.f / 192.f) - mu * mu;
      float rs  = rsqrtf(var + 1e-6f);
      sm.misc[side * 192 + w]      = mu;
      sm.misc[side * 192 + 96 + w] = rs;
    }
  }

  // phase 3: V^T = W2 * X^T  -> vtl/vtr (stride 104)   (D[m=c][n=x])
  // bv loaded transiently from L2-hot global inside the phase.
  #pragma unroll
  for (int sd = 0; sd < 2; ++sd) {
    const short* Wb = sd ? W2r_b : W2l_b;
    const short* Xb = sd ? sm.buf2 : sm.buf1;
    short* Vt = sd ? sm.vtr : sm.vtl;
    const float* bvg = sd ? br2 : bl2;
    float bv[4];
    #pragma unroll
    for (int j = 0; j < 4; ++j) bv[j] = bvg[wid * 16 + r4 + j];
    bhalf8 af[6];
    #pragma unroll
    for (int k = 0; k < 6; ++k)
      af[k] = *reinterpret_cast<const bhalf8*>(Wb + o_wm * 192 + k * 32 + kc8);
    #pragma unroll
    for (int xi = 0; xi < 6; ++xi) {
      const int row = xi * 16 + m16;
      const int kxr = (row >> 2) & 7;
      const short* Xr = Xb + row * 200;
      f32x4 acc = {0.f, 0.f, 0.f, 0.f};
      #pragma unroll
      for (int k = 0; k < 6; ++k) {
        bhalf8 bfr = *reinterpret_cast<const bhalf8*>(Xr + (((k * 4 + hb) ^ kxr) << 3));
        acc = __builtin_amdgcn_mfma_f32_16x16x32_bf16(af[k], bfr, acc, 0, 0, 0);
      }
      const int xcol = xi * 16 + m16;
      #pragma unroll
      for (int j = 0; j < 4; ++j) {
        int cr = wid * 16 + r4 + j;
        Vt[cr * PS + xcol] = (short)f2bf(acc[j] + bv[j]);
      }
    }
  }

  // phase 4: Q projections into registers (D[m=x][n=o]); W1 frags scoped here
  f32x4 accQ0[6], accQ1[6];
  {
    {
      bhalf8 bfq[6];
      #pragma unroll
      for (int k = 0; k < 6; ++k)
        bfq[k] = *reinterpret_cast<const bhalf8*>(W1l_b + o_wm * 192 + k * 32 + kc8);
      #pragma unroll
      for (int mi = 0; mi < 6; ++mi) {
        const int row = mi * 16 + m16;
        const int kxr = (row >> 2) & 7;
        const short* Xr = sm.buf1 + row * 200;
        f32x4 acc = {0.f, 0.f, 0.f, 0.f};
        #pragma unroll
        for (int k = 0; k < 6; ++k) {
          bhalf8 afr = *reinterpret_cast<const bhalf8*>(Xr + (((k * 4 + hb) ^ kxr) << 3));
          acc = __builtin_amdgcn_mfma_f32_16x16x32_bf16(afr, bfq[k], acc, 0, 0, 0);
        }
        accQ0[mi] = acc;
      }
    }
    {
      bhalf8 bfq[6];
      #pragma unroll
      for (int k = 0; k < 6; ++k)
        bfq[k] = *reinterpret_cast<const bhalf8*>(W1r_b + o_wm * 192 + k * 32 + kc8);
      #pragma unroll
      for (int mi = 0; mi < 6; ++mi) {
        const int row = mi * 16 + m16;
        const int kxr = (row >> 2) & 7;
        const short* Xr = sm.buf2 + row * 200;
        f32x4 acc = {0.f, 0.f, 0.f, 0.f};
        #pragma unroll
        for (int k = 0; k < 6; ++k) {
          bhalf8 afr = *reinterpret_cast<const bhalf8*>(Xr + (((k * 4 + hb) ^ kxr) << 3));
          acc = __builtin_amdgcn_mfma_f32_16x16x32_bf16(afr, bfq[k], acc, 0, 0, 0);
        }
        accQ1[mi] = acc;
      }
    }
  }
  __syncthreads();
  // phase 4b: write Q with folded LN affine: Q = rs*acc - mu*rs*s1[o] + t1[o]
  // s1/t1 loaded transiently from L2-hot global.
  {
    const int o = o_wm;
    const int ob = o & 7;
    #pragma unroll
    for (int sd = 0; sd < 2; ++sd) {
      short* Qb = sd ? sm.buf2 : sm.buf1;
      const float* muA = sm.misc + sd * 192;
      const float* rsA = muA + 96;
      float s1o = (sd ? s1r : s1l)[o];
      float t1o = (sd ? t1r : t1l)[o];
      #pragma unroll
      for (int mi = 0; mi < 6; ++mi) {
        const int kx = (4 * mi + hb) & 7;        // (x>>2)&7 for x = mi*16+r4+j
        const int swo = (((o >> 3) ^ kx) << 3) | ob;
        f32x4 acc = sd ? accQ1[mi] : accQ0[mi];
        #pragma unroll
        for (int j = 0; j < 4; ++j) {
          int x = mi * 16 + r4 + j;
          float mu = muA[x], rs = rsA[x];
          Qb[x * 200 + swo] = (short)f2bf(rs * acc[j] - mu * rs * s1o + t1o);
        }
      }
    }
  }
  __syncthreads();

  // phase 5: att = Q_l * Q_r^T (scaled) -> fp32 over buf1, stride 100 dwords,
  // column swizzle y ^ (x&31)
  {
    const int mi = wid >> 1;
    const int yb = (wid & 1) * 3;
    const int arow = mi * 16 + m16;
    const int kxa = (arow >> 2) & 7;
    bhalf8 afa[6];
    #pragma unroll
    for (int k = 0; k < 6; ++k)
      afa[k] = *reinterpret_cast<const bhalf8*>(sm.buf1 + arow * 200 + (((k * 4 + hb) ^ kxa) << 3));
    f32x4 accA[3];
    #pragma unroll
    for (int yt = 0; yt < 3; ++yt) {
      const int brow = (yb + yt) * 16 + m16;
      const int kxb = (brow >> 2) & 7;
      const short* Br = sm.buf2 + brow * 200;
      f32x4 acc = {0.f, 0.f, 0.f, 0.f};
      #pragma unroll
      for (int k = 0; k < 6; ++k) {
        bhalf8 bfy = *reinterpret_cast<const bhalf8*>(Br + (((k * 4 + hb) ^ kxb) << 3));
        acc = __builtin_amdgcn_mfma_f32_16x16x32_bf16(afa[k], bfy, acc, 0, 0, 0);
      }
      accA[yt] = acc;
    }
    __syncthreads();
    float* attf = reinterpret_cast<float*>(sm.buf1);
    const float scale = 0.07216878364870323f;   // 192^-0.5
    #pragma unroll
    for (int yt = 0; yt < 3; ++yt) {
      #pragma unroll
      for (int j = 0; j < 4; ++j) {
        int x = mi * 16 + r4 + j;
        int y = (yb + yt) * 16 + m16;
        attf[x * AS + (y ^ (x & 31))] = accA[yt][j] * scale;
      }
    }
  }
  __syncthreads();

  // phase 6: dual softmax -> P_row (bf16 [x][y], stride 104) and P_colT ([y][x])
  {
    const float* attf = reinterpret_cast<const float*>(sm.buf1);
    short* Pr = sm.buf2;
    short* Pc = sm.buf2 + 96 * PS;
    const int r = tid >> 3;     // 0..95
    const int p = tid & 7;
    {   // row softmax (over y), r = x
      float av[12];
      #pragma unroll
      for (int k = 0; k < 12; ++k)
        av[k] = attf[r * AS + ((p * 12 + k) ^ (r & 31))];
      float mx = av[0];
      #pragma unroll
      for (int k = 1; k < 12; ++k) mx = fmaxf(mx, av[k]);
      mx = fmaxf(mx, __shfl_xor(mx, 1));
      mx = fmaxf(mx, __shfl_xor(mx, 2));
      mx = fmaxf(mx, __shfl_xor(mx, 4));
      float s = 0.f;
      #pragma unroll
      for (int k = 0; k < 12; ++k) { av[k] = __expf(av[k] - mx); s += av[k]; }
      s += __shfl_xor(s, 1); s += __shfl_xor(s, 2); s += __shfl_xor(s, 4);
      float inv = 1.f / s;
      #pragma unroll
      for (int k = 0; k < 12; k += 2) {
        unsigned u = (unsigned)f2bf(av[k] * inv) | ((unsigned)f2bf(av[k + 1] * inv) << 16);
        *reinterpret_cast<unsigned*>(Pr + r * PS + p * 12 + k) = u;
      }
    }
    {   // column softmax (over x), r = y; write transposed
      float av[12];
      #pragma unroll
      for (int k = 0; k < 12; ++k) {
        int x = p * 12 + k;
        av[k] = attf[x * AS + (r ^ (x & 31))];
      }
      float mx = av[0];
      #pragma unroll
      for (int k = 1; k < 12; ++k) mx = fmaxf(mx, av[k]);
      mx = fmaxf(mx, __shfl_xor(mx, 1));
      mx = fmaxf(mx, __shfl_xor(mx, 2));
      mx = fmaxf(mx, __shfl_xor(mx, 4));
      float s = 0.f;
      #pragma unroll
      for (int k = 0; k < 12; ++k) { av[k] = __expf(av[k] - mx); s += av[k]; }
      s += __shfl_xor(s, 1); s += __shfl_xor(s, 2); s += __shfl_xor(s, 4);
      float inv = 1.f / s;
      #pragma unroll
      for (int k = 0; k < 12; k += 2) {
        unsigned u = (unsigned)f2bf(av[k] * inv) | ((unsigned)f2bf(av[k + 1] * inv) << 16);
        *reinterpret_cast<unsigned*>(Pc + r * PS + p * 12 + k) = u;
      }
    }
  }
  __syncthreads();

  // phase 7: F_r2l = P_row * V_r, F_l2r = P_colT * V_l   (D[m=x|y][n=c])
  f32x4 accF[6], accG[6];
  {
    const short* Pr = sm.buf2;
    const short* Pc = sm.buf2 + 96 * PS;
    bhalf8 vf[3], vg[3];
    #pragma unroll
    for (int k = 0; k < 3; ++k) {
      vf[k] = *reinterpret_cast<const bhalf8*>(sm.vtr + o_wm * PS + k * 32 + kc8);
      vg[k] = *reinterpret_cast<const bhalf8*>(sm.vtl + o_wm * PS + k * 32 + kc8);
    }
    #pragma unroll
    for (int xi = 0; xi < 6; ++xi) {
      f32x4 a1 = {0.f, 0.f, 0.f, 0.f}, a2 = {0.f, 0.f, 0.f, 0.f};
      #pragma unroll
      for (int k = 0; k < 3; ++k) {
        bhalf8 ap = *reinterpret_cast<const bhalf8*>(Pr + (xi * 16 + m16) * PS + k * 32 + kc8);
        a1 = __builtin_amdgcn_mfma_f32_16x16x32_bf16(ap, vf[k], a1, 0, 0, 0);
        bhalf8 aq = *reinterpret_cast<const bhalf8*>(Pc + (xi * 16 + m16) * PS + k * 32 + kc8);
        a2 = __builtin_amdgcn_mfma_f32_16x16x32_bf16(aq, vg[k], a2, 0, 0, 0);
      }
      accF[xi] = a1; accG[xi] = a2;
    }
  }
  __syncthreads();
  {
    const int cc2 = o_wm;
    const int ob = cc2 & 7;
    #pragma unroll
    for (int xi = 0; xi < 6; ++xi) {
      const int kx = (4 * xi + hb) & 7;
      const int swo = ((((cc2 >> 3) ^ kx) << 3) | ob);
      #pragma unroll
      for (int j = 0; j < 4; ++j) {
        int x = xi * 16 + r4 + j;
        sm.buf1[x * 200 + swo] = (short)f2bf(accF[xi][j]);   // F_r2l [x][c]
        sm.buf2[x * 200 + swo] = (short)f2bf(accG[xi][j]);   // F_l2r [y][c]
      }
    }
  }
  __syncthreads();

  // phase 8: epilogue  out = x + F*coef + temb  (coalesced global, swizzled F;
  // x re-read is L2/L3-hot when no scratch traffic competes for cache)
  #pragma unroll
  for (int sd = 0; sd < 2; ++sd) {
    const float* xg = sd ? x_r : x_l;
    float* og = out + (sd ? HALF_OUT : 0);
    const short* Fb = sd ? sm.buf2 : sm.buf1;
    const float* coef = sm.misc + (sd ? 768 : 576);
    #pragma unroll
    for (int j = 0; j < 6; ++j) {
      int i4 = j * 768 + tid;
      int c  = i4 / 24;
      int w4 = i4 - c * 24;
      const float4 xv = *reinterpret_cast<const float4*>(xg + sliceBase + c * HWc + w4 * 4);
      float cf = coef[c];
      float tv = sm.misc[384 + c];
      int sw = ((((c >> 3) ^ (w4 & 7)) << 3) | (c & 7));
      int fb = w4 * 800 + sw;
      float4 ov;
      ov.x = xv.x + bf2f_s(Fb[fb      ]) * cf + tv;
      ov.y = xv.y + bf2f_s(Fb[fb + 200]) * cf + tv;
      ov.z = xv.z + bf2f_s(Fb[fb + 400]) * cf + tv;
      ov.w = xv.w + bf2f_s(Fb[fb + 600]) * cf + tv;
      *reinterpret_cast<float4*>(og + sliceBase + c * HWc + w4 * 4) = ov;
    }
  }
}

// -------------------------------------------------------------------- host ---
extern "C" void kernel_launch(void* const* d_in, const int* in_sizes, int n_in,
                              void* d_out, int out_size, void* d_ws, size_t ws_size,
                              hipStream_t stream)
{
  const float* t    = (const float*)d_in[0];
  const float* x_l  = (const float*)d_in[1];
  const float* x_r  = (const float*)d_in[2];
  const float* lnwl = (const float*)d_in[3];
  const float* lnbl = (const float*)d_in[4];
  const float* lnwr = (const float*)d_in[5];
  const float* lnbr = (const float*)d_in[6];
  const float* Wl1  = (const float*)d_in[7];
  const float* bl1  = (const float*)d_in[8];
  const float* Wr1  = (const float*)d_in[9];
  const float* br1  = (const float*)d_in[10];
  const float* Wl2  = (const float*)d_in[11];
  const float* bl2  = (const float*)d_in[12];
  const float* Wr2  = (const float*)d_in[13];
  const float* br2  = (const float*)d_in[14];
  const float* beta = (const float*)d_in[15];
  const float* gamma= (const float*)d_in[16];
  const float* Wt   = (const float*)d_in[17];
  const float* bt   = (const float*)d_in[18];
  float* out = (float*)d_out;

  char* ws = (char*)d_ws;
  short* W1l_b = (short*)ws;
  short* W1r_b = W1l_b + 36864;
  short* W2l_b = W1r_b + 36864;
  short* W2r_b = W2l_b + 36864;
  float* fws  = (float*)(ws + 4 * 73728);
  float* s1l  = fws;
  float* t1l  = fws + 192;
  float* s1r  = fws + 384;
  float* t1r  = fws + 576;
  float* temb = fws + 768;   // 3072 floats
  float* mt   = fws + 3840;  // 8192 floats

  setup1<<<610, 256, 0, stream>>>(t, lnwl, lnbl, lnwr, lnbr, Wl1, bl1, Wr1, br1,
                                  Wl2, Wr2, W1l_b, W1r_b, W2l_b, W2r_b,
                                  s1l, t1l, s1r, t1r, mt);
  setup2<<<12, 256, 0, stream>>>(mt, Wt, bt, temb);
  scam_main<<<1536, 768, 0, stream>>>(x_l, x_r, bl2, br2, beta, gamma,
                                      W1l_b, W1r_b, W2l_b, W2r_b,
                                      s1l, t1l, s1r, t1r, temb, out);
}

// Round 8
// 262.682 us; speedup vs baseline: 3.1532x; 1.0030x over previous
//
#include <hip/hip_runtime.h>
#include <hip/hip_bf16.h>

// SCAM fused kernel for MI355X (gfx950).
// One workgroup per (b,h) attention slice; everything (LN, 4 projections,
// QK^T, dual softmax, 2x PV, epilogue) stays in LDS.
// R8 = R7 with the compile fix: pk2bf built from two scalar hw converts
// (__hip_bfloat162 is not trivially copyable for __builtin_bit_cast).
// R7 changes: (a) swapped MFMA operands in phases 3/4/7 so D gives each lane
// 4 row-consecutive outputs -> packed ds_write_b64 instead of 48 scalar
// column-strided b16 writes per wave (the conflict mass), (b) hardware
// bf16 converts via __float2bfloat16.

typedef __attribute__((ext_vector_type(8))) short bhalf8;   // 8 bf16 in 4 VGPRs
typedef __attribute__((ext_vector_type(4))) float f32x4;

#define DEVI static __device__ __forceinline__

constexpr int Cc   = 192;
constexpr int HWc  = 9216;          // 96*96
constexpr int CHW  = 192 * 9216;    // per-batch image
constexpr int HALF_OUT = 16 * CHW;  // 28311552
constexpr int PS   = 104;           // padded row stride (halves) for P and Vt
constexpr int AS   = 100;           // att row stride (dwords)

DEVI unsigned short f2bf(float f) {           // hw cvt (RNE) via hip_bf16
  __hip_bfloat16 h = __float2bfloat16(f);
  return __builtin_bit_cast(unsigned short, h);
}
DEVI unsigned pk2bf(float a, float b) {       // packed pair: a -> low, b -> high
  return (unsigned)f2bf(a) | ((unsigned)f2bf(b) << 16);
}
DEVI float bf2f(unsigned short h) {
  unsigned u = (unsigned)h << 16;
  return __builtin_bit_cast(float, u);
}
DEVI float bf2f_s(short h) { return bf2f((unsigned short)h); }

// ---------------------------------------------------------------- setup 1 ---
__global__ void setup1(
    const float* __restrict__ t,
    const float* __restrict__ lnwl, const float* __restrict__ lnbl,
    const float* __restrict__ lnwr, const float* __restrict__ lnbr,
    const float* __restrict__ Wl1, const float* __restrict__ bl1,
    const float* __restrict__ Wr1, const float* __restrict__ br1,
    const float* __restrict__ Wl2, const float* __restrict__ Wr2,
    short* __restrict__ W1l_b, short* __restrict__ W1r_b,
    short* __restrict__ W2l_b, short* __restrict__ W2r_b,
    float* __restrict__ s1l, float* __restrict__ t1l,
    float* __restrict__ s1r, float* __restrict__ t1r,
    float* __restrict__ mt)
{
  const int blk = blockIdx.x, tid = threadIdx.x;
  if (blk < 576) {
    int id  = blk * 256 + tid;          // < 147456
    int m   = id / 36864;
    int rem = id - m * 36864;
    int c   = rem % 192;
    float v;
    short* dst;
    if (m == 0)      { v = lnwl[c] * Wl1[rem]; dst = W1l_b; }
    else if (m == 1) { v = lnwr[c] * Wr1[rem]; dst = W1r_b; }
    else if (m == 2) { v = Wl2[rem];           dst = W2l_b; }
    else             { v = Wr2[rem];           dst = W2r_b; }
    dst[rem] = (short)f2bf(v);
  } else if (blk == 576 || blk == 577) {
    if (tid < 192) {
      const float* Wm = (blk == 576) ? Wl1 : Wr1;
      const float* lw = (blk == 576) ? lnwl : lnwr;
      const float* lb = (blk == 576) ? lnbl : lnbr;
      const float* bb = (blk == 576) ? bl1 : br1;
      float s = 0.f, tb = 0.f;
      for (int c = 0; c < 192; ++c) {
        float wv = Wm[tid * 192 + c];
        s  += lw[c] * wv;
        tb += lb[c] * wv;
      }
      if (blk == 576) { s1l[tid] = s; t1l[tid] = tb + bb[tid]; }
      else            { s1r[tid] = s; t1r[tid] = tb + bb[tid]; }
    }
  } else {
    int id = (blk - 578) * 256 + tid;   // < 8192
    float v = t[id];
    float sp = (v > 20.f) ? v : log1pf(__expf(v));
    mt[id] = v * tanhf(sp);
  }
}

// temb[b][o] = sum_k mish(t)[b][k] * Wt[o][k] + bt[o]
__global__ void setup2(const float* __restrict__ mt, const float* __restrict__ Wt,
                       const float* __restrict__ bt, float* __restrict__ temb)
{
  int id = blockIdx.x * 256 + threadIdx.x;  // < 3072
  int b = id / 192, o = id - b * 192;
  float s = 0.f;
  for (int k = 0; k < 512; ++k) s += mt[b * 512 + k] * Wt[o * 512 + k];
  temb[id] = s + bt[o];
}

// ------------------------------------------------------------- main kernel ---
// misc layout (floats): 0 mu_l[96], 96 rs_l[96], 192 mu_r[96], 288 rs_r[96],
// 384 te[192], 576 beta[192], 768 gamma[192]   (end 960)
struct SmemT {
  short buf1[96 * 200];   // XT_l -> Q_l -> att(fp32, stride 100dw) -> F_r2l 38400 B
  short buf2[19968];      // XT_r -> Q_r -> P_row/P_colT -> F_l2r            39936 B
  short vtl[192 * PS];    // V_l^T [c][x] stride 104                         39936 B
  short vtr[192 * PS];    // V_r^T [c][y] stride 104                         39936 B
  float misc[960];        //                                                  3840 B
};
static_assert(sizeof(SmemT) <= 163840, "LDS overflow");

__launch_bounds__(768, 3)
__global__ void scam_main(
    const float* __restrict__ x_l, const float* __restrict__ x_r,
    const float* __restrict__ bl2, const float* __restrict__ br2,
    const float* __restrict__ beta, const float* __restrict__ gamma,
    const short* __restrict__ W1l_b, const short* __restrict__ W1r_b,
    const short* __restrict__ W2l_b, const short* __restrict__ W2r_b,
    const float* __restrict__ s1l, const float* __restrict__ t1l,
    const float* __restrict__ s1r, const float* __restrict__ t1r,
    const float* __restrict__ temb,
    float* __restrict__ out)
{
  __shared__ SmemT sm;
  const int tid  = threadIdx.x;
  const int lane = tid & 63;
  const int wid  = tid >> 6;            // 0..11
  const int m16  = lane & 15;
  const int hb   = lane >> 4;           // 0..3
  const int kc8  = hb * 8;              // element offset within a fragment row
  const int r4   = hb * 4;              // D-row base
  const int slice = blockIdx.x;
  const int bb_ = slice / 96;
  const int hh_ = slice - bb_ * 96;
  const int sliceBase = bb_ * CHW + hh_ * 96;
  const int o_wm = wid * 16 + m16;

  // phase 0: small vectors into LDS (te, beta, gamma)
  if (tid < 576) {
    int a = tid / 192, o = tid - a * 192;
    if (a == 0)      sm.misc[384 + o] = temb[bb_ * 192 + o];
    else if (a == 1) sm.misc[576 + o] = beta[o];
    else             sm.misc[768 + o] = gamma[o];
  }

  // phase 1: stage x -> bf16 [w][c] rows (stride 200), coalesced global reads,
  // block-XOR LDS swizzle: element (w,c) at w*200 + ((c>>3)^((w>>2)&7))*8 + (c&7)
  #pragma unroll
  for (int j = 0; j < 6; ++j) {
    int i4 = j * 768 + tid;             // < 4608
    int c  = i4 / 24;
    int w4 = i4 - c * 24;               // w = 4*w4 + r, (w>>2)&7 = w4&7
    const float4 xl4 = *reinterpret_cast<const float4*>(x_l + sliceBase + c * HWc + w4 * 4);
    const float4 xr4 = *reinterpret_cast<const float4*>(x_r + sliceBase + c * HWc + w4 * 4);
    int sw = ((((c >> 3) ^ (w4 & 7)) << 3) | (c & 7));
    int base = w4 * 800 + sw;
    sm.buf1[base      ] = (short)f2bf(xl4.x);
    sm.buf1[base + 200] = (short)f2bf(xl4.y);
    sm.buf1[base + 400] = (short)f2bf(xl4.z);
    sm.buf1[base + 600] = (short)f2bf(xl4.w);
    sm.buf2[base      ] = (short)f2bf(xr4.x);
    sm.buf2[base + 200] = (short)f2bf(xr4.y);
    sm.buf2[base + 400] = (short)f2bf(xr4.z);
    sm.buf2[base + 600] = (short)f2bf(xr4.w);
  }
  __syncthreads();

  // phase 2: LN stats per pixel (reads swizzled blocks; sum order irrelevant)
  {
    int side = (tid >= 384) ? 1 : 0;
    int rest = tid - side * 384;
    int w = rest >> 2;
    int q = rest & 3;
    const short* Xb = side ? sm.buf2 : sm.buf1;
    const int kxw = (w >> 2) & 7;
    float s0 = 0.f, s2 = 0.f;
    #pragma unroll
    for (int mc = 0; mc < 6; ++mc) {
      bhalf8 v = *reinterpret_cast<const bhalf8*>(Xb + w * 200 + (((q * 6 + mc) ^ kxw) << 3));
      #pragma unroll
      for (int e = 0; e < 8; ++e) { float f = bf2f_s(v[e]); s0 += f; s2 += f * f; }
    }
    s0 += __shfl_xor(s0, 1); s2 += __shfl_xor(s2, 1);
    s0 += __shfl_xor(s0, 2); s2 += __shfl_xor(s2, 2);
    if (q == 0) {
      float mu  = s0 * (1.f / 192.f);
      float var = s2 * (1.f / 192.f) - mu * mu;
      float rs  = rsqrtf(var + 1e-6f);
      sm.misc[side * 192 + w]      = mu;
      sm.misc[side * 192 + 96 + w] = rs;
    }
  }

  // phase 3: V^T -> vtl/vtr (stride 104). Swapped operands: D[m=x][n=c];
  // lane holds 4 consecutive x for c = wid*16+m16 -> packed ds_write_b64.
  #pragma unroll
  for (int sd = 0; sd < 2; ++sd) {
    const short* Wb = sd ? W2r_b : W2l_b;
    const short* Xb = sd ? sm.buf2 : sm.buf1;
    short* Vt = sd ? sm.vtr : sm.vtl;
    const float bv = (sd ? br2 : bl2)[o_wm];   // c = o_wm per lane
    bhalf8 af[6];
    #pragma unroll
    for (int k = 0; k < 6; ++k)
      af[k] = *reinterpret_cast<const bhalf8*>(Wb + o_wm * 192 + k * 32 + kc8);
    #pragma unroll
    for (int xi = 0; xi < 6; ++xi) {
      const int row = xi * 16 + m16;
      const int kxr = (row >> 2) & 7;
      const short* Xr = Xb + row * 200;
      f32x4 acc = {0.f, 0.f, 0.f, 0.f};
      #pragma unroll
      for (int k = 0; k < 6; ++k) {
        bhalf8 bfr = *reinterpret_cast<const bhalf8*>(Xr + (((k * 4 + hb) ^ kxr) << 3));
        acc = __builtin_amdgcn_mfma_f32_16x16x32_bf16(bfr, af[k], acc, 0, 0, 0);
      }
      // D[m=x][n=c]: lane (m16,hb): x = xi*16 + r4 + j, c = o_wm
      uint2 pv;
      pv.x = pk2bf(acc[0] + bv, acc[1] + bv);
      pv.y = pk2bf(acc[2] + bv, acc[3] + bv);
      *reinterpret_cast<uint2*>(Vt + o_wm * PS + xi * 16 + r4) = pv;
    }
  }

  // phase 4: Q projections, swapped: D[m=o][n=x]; lane holds 4 consecutive o
  // for x = mi*16+m16 -> packed b64 Q writes in phase 4b.
  f32x4 accQ0[6], accQ1[6];
  {
    {
      bhalf8 bfq[6];
      #pragma unroll
      for (int k = 0; k < 6; ++k)
        bfq[k] = *reinterpret_cast<const bhalf8*>(W1l_b + o_wm * 192 + k * 32 + kc8);
      #pragma unroll
      for (int mi = 0; mi < 6; ++mi) {
        const int row = mi * 16 + m16;
        const int kxr = (row >> 2) & 7;
        const short* Xr = sm.buf1 + row * 200;
        f32x4 acc = {0.f, 0.f, 0.f, 0.f};
        #pragma unroll
        for (int k = 0; k < 6; ++k) {
          bhalf8 afr = *reinterpret_cast<const bhalf8*>(Xr + (((k * 4 + hb) ^ kxr) << 3));
          acc = __builtin_amdgcn_mfma_f32_16x16x32_bf16(bfq[k], afr, acc, 0, 0, 0);
        }
        accQ0[mi] = acc;
      }
    }
    {
      bhalf8 bfq[6];
      #pragma unroll
      for (int k = 0; k < 6; ++k)
        bfq[k] = *reinterpret_cast<const bhalf8*>(W1r_b + o_wm * 192 + k * 32 + kc8);
      #pragma unroll
      for (int mi = 0; mi < 6; ++mi) {
        const int row = mi * 16 + m16;
        const int kxr = (row >> 2) & 7;
        const short* Xr = sm.buf2 + row * 200;
        f32x4 acc = {0.f, 0.f, 0.f, 0.f};
        #pragma unroll
        for (int k = 0; k < 6; ++k) {
          bhalf8 afr = *reinterpret_cast<const bhalf8*>(Xr + (((k * 4 + hb) ^ kxr) << 3));
          acc = __builtin_amdgcn_mfma_f32_16x16x32_bf16(bfq[k], afr, acc, 0, 0, 0);
        }
        accQ1[mi] = acc;
      }
    }
  }
  __syncthreads();
  // phase 4b: Q = rs*acc - mu*rs*s1[o] + t1[o]; D[m=o][n=x]: lane has
  // o = wid*16 + r4 + j (4 values), x = mi*16 + m16. Packed b64 writes.
  {
    const int obase = wid * 16 + r4;          // 4 consecutive o
    const int oblk  = obase >> 3;             // 2*wid + (hb>>1)
    const int osub  = (hb & 1) * 4;           // (o&7) base
    #pragma unroll
    for (int sd = 0; sd < 2; ++sd) {
      short* Qb = sd ? sm.buf2 : sm.buf1;
      const float* muA = sm.misc + sd * 192;
      const float* rsA = muA + 96;
      const float* s1g = sd ? s1r : s1l;
      const float* t1g = sd ? t1r : t1l;
      float s1v[4], t1v[4];
      #pragma unroll
      for (int j = 0; j < 4; ++j) { s1v[j] = s1g[obase + j]; t1v[j] = t1g[obase + j]; }
      #pragma unroll
      for (int mi = 0; mi < 6; ++mi) {
        const int x = mi * 16 + m16;
        const int kx = (x >> 2) & 7;
        float mu = muA[x], rs = rsA[x];
        float mrs = mu * rs;
        f32x4 acc = sd ? accQ1[mi] : accQ0[mi];
        float q0 = rs * acc[0] - mrs * s1v[0] + t1v[0];
        float q1 = rs * acc[1] - mrs * s1v[1] + t1v[1];
        float q2 = rs * acc[2] - mrs * s1v[2] + t1v[2];
        float q3 = rs * acc[3] - mrs * s1v[3] + t1v[3];
        uint2 pv;
        pv.x = pk2bf(q0, q1);
        pv.y = pk2bf(q2, q3);
        *reinterpret_cast<uint2*>(Qb + x * 200 + (((oblk ^ kx) << 3) | osub)) = pv;
      }
    }
  }
  __syncthreads();

  // phase 5: att = Q_l * Q_r^T (scaled) -> fp32 over buf1, stride 100 dwords,
  // column swizzle y ^ (x&31)
  {
    const int mi = wid >> 1;
    const int yb = (wid & 1) * 3;
    const int arow = mi * 16 + m16;
    const int kxa = (arow >> 2) & 7;
    bhalf8 afa[6];
    #pragma unroll
    for (int k = 0; k < 6; ++k)
      afa[k] = *reinterpret_cast<const bhalf8*>(sm.buf1 + arow * 200 + (((k * 4 + hb) ^ kxa) << 3));
    f32x4 accA[3];
    #pragma unroll
    for (int yt = 0; yt < 3; ++yt) {
      const int brow = (yb + yt) * 16 + m16;
      const int kxb = (brow >> 2) & 7;
      const short* Br = sm.buf2 + brow * 200;
      f32x4 acc = {0.f, 0.f, 0.f, 0.f};
      #pragma unroll
      for (int k = 0; k < 6; ++k) {
        bhalf8 bfy = *reinterpret_cast<const bhalf8*>(Br + (((k * 4 + hb) ^ kxb) << 3));
        acc = __builtin_amdgcn_mfma_f32_16x16x32_bf16(afa[k], bfy, acc, 0, 0, 0);
      }
      accA[yt] = acc;
    }
    __syncthreads();
    float* attf = reinterpret_cast<float*>(sm.buf1);
    const float scale = 0.07216878364870323f;   // 192^-0.5
    #pragma unroll
    for (int yt = 0; yt < 3; ++yt) {
      #pragma unroll
      for (int j = 0; j < 4; ++j) {
        int x = mi * 16 + r4 + j;
        int y = (yb + yt) * 16 + m16;
        attf[x * AS + (y ^ (x & 31))] = accA[yt][j] * scale;
      }
    }
  }
  __syncthreads();

  // phase 6: dual softmax -> P_row (bf16 [x][y], stride 104) and P_colT ([y][x])
  {
    const float* attf = reinterpret_cast<const float*>(sm.buf1);
    short* Pr = sm.buf2;
    short* Pc = sm.buf2 + 96 * PS;
    const int r = tid >> 3;     // 0..95
    const int p = tid & 7;
    {   // row softmax (over y), r = x
      float av[12];
      #pragma unroll
      for (int k = 0; k < 12; ++k)
        av[k] = attf[r * AS + ((p * 12 + k) ^ (r & 31))];
      float mx = av[0];
      #pragma unroll
      for (int k = 1; k < 12; ++k) mx = fmaxf(mx, av[k]);
      mx = fmaxf(mx, __shfl_xor(mx, 1));
      mx = fmaxf(mx, __shfl_xor(mx, 2));
      mx = fmaxf(mx, __shfl_xor(mx, 4));
      float s = 0.f;
      #pragma unroll
      for (int k = 0; k < 12; ++k) { av[k] = __expf(av[k] - mx); s += av[k]; }
      s += __shfl_xor(s, 1); s += __shfl_xor(s, 2); s += __shfl_xor(s, 4);
      float inv = 1.f / s;
      #pragma unroll
      for (int k = 0; k < 12; k += 2) {
        *reinterpret_cast<unsigned*>(Pr + r * PS + p * 12 + k) =
            pk2bf(av[k] * inv, av[k + 1] * inv);
      }
    }
    {   // column softmax (over x), r = y; write transposed
      float av[12];
      #pragma unroll
      for (int k = 0; k < 12; ++k) {
        int x = p * 12 + k;
        av[k] = attf[x * AS + (r ^ (x & 31))];
      }
      float mx = av[0];
      #pragma unroll
      for (int k = 1; k < 12; ++k) mx = fmaxf(mx, av[k]);
      mx = fmaxf(mx, __shfl_xor(mx, 1));
      mx = fmaxf(mx, __shfl_xor(mx, 2));
      mx = fmaxf(mx, __shfl_xor(mx, 4));
      float s = 0.f;
      #pragma unroll
      for (int k = 0; k < 12; ++k) { av[k] = __expf(av[k] - mx); s += av[k]; }
      s += __shfl_xor(s, 1); s += __shfl_xor(s, 2); s += __shfl_xor(s, 4);
      float inv = 1.f / s;
      #pragma unroll
      for (int k = 0; k < 12; k += 2) {
        *reinterpret_cast<unsigned*>(Pc + r * PS + p * 12 + k) =
            pk2bf(av[k] * inv, av[k + 1] * inv);
      }
    }
  }
  __syncthreads();

  // phase 7: F_r2l = P_row * V_r, F_l2r = P_colT * V_l. Swapped: D[m=c][n=x];
  // lane holds 4 consecutive c for x = xi*16+m16 -> packed b64 F writes.
  f32x4 accF[6], accG[6];
  {
    const short* Pr = sm.buf2;
    const short* Pc = sm.buf2 + 96 * PS;
    bhalf8 vf[3], vg[3];
    #pragma unroll
    for (int k = 0; k < 3; ++k) {
      vf[k] = *reinterpret_cast<const bhalf8*>(sm.vtr + o_wm * PS + k * 32 + kc8);
      vg[k] = *reinterpret_cast<const bhalf8*>(sm.vtl + o_wm * PS + k * 32 + kc8);
    }
    #pragma unroll
    for (int xi = 0; xi < 6; ++xi) {
      f32x4 a1 = {0.f, 0.f, 0.f, 0.f}, a2 = {0.f, 0.f, 0.f, 0.f};
      #pragma unroll
      for (int k = 0; k < 3; ++k) {
        bhalf8 ap = *reinterpret_cast<const bhalf8*>(Pr + (xi * 16 + m16) * PS + k * 32 + kc8);
        a1 = __builtin_amdgcn_mfma_f32_16x16x32_bf16(vf[k], ap, a1, 0, 0, 0);
        bhalf8 aq = *reinterpret_cast<const bhalf8*>(Pc + (xi * 16 + m16) * PS + k * 32 + kc8);
        a2 = __builtin_amdgcn_mfma_f32_16x16x32_bf16(vg[k], aq, a2, 0, 0, 0);
      }
      accF[xi] = a1; accG[xi] = a2;
    }
  }
  __syncthreads();
  {
    const int cblk = (wid * 16 + r4) >> 3;    // 2*wid + (hb>>1)
    const int csub = (hb & 1) * 4;
    #pragma unroll
    for (int xi = 0; xi < 6; ++xi) {
      const int x = xi * 16 + m16;
      const int kx = (x >> 2) & 7;
      const int off = x * 200 + (((cblk ^ kx) << 3) | csub);
      uint2 pf, pg;
      pf.x = pk2bf(accF[xi][0], accF[xi][1]);
      pf.y = pk2bf(accF[xi][2], accF[xi][3]);
      pg.x = pk2bf(accG[xi][0], accG[xi][1]);
      pg.y = pk2bf(accG[xi][2], accG[xi][3]);
      *reinterpret_cast<uint2*>(sm.buf1 + off) = pf;   // F_r2l [x][c]
      *reinterpret_cast<uint2*>(sm.buf2 + off) = pg;   // F_l2r [y][c]
    }
  }
  __syncthreads();

  // phase 8: epilogue  out = x + F*coef + temb  (coalesced global, swizzled F;
  // x re-read is L2/L3-hot)
  #pragma unroll
  for (int sd = 0; sd < 2; ++sd) {
    const float* xg = sd ? x_r : x_l;
    float* og = out + (sd ? HALF_OUT : 0);
    const short* Fb = sd ? sm.buf2 : sm.buf1;
    const float* coef = sm.misc + (sd ? 768 : 576);
    #pragma unroll
    for (int j = 0; j < 6; ++j) {
      int i4 = j * 768 + tid;
      int c  = i4 / 24;
      int w4 = i4 - c * 24;
      const float4 xv = *reinterpret_cast<const float4*>(xg + sliceBase + c * HWc + w4 * 4);
      float cf = coef[c];
      float tv = sm.misc[384 + c];
      int sw = ((((c >> 3) ^ (w4 & 7)) << 3) | (c & 7));
      int fb = w4 * 800 + sw;
      float4 ov;
      ov.x = xv.x + bf2f_s(Fb[fb      ]) * cf + tv;
      ov.y = xv.y + bf2f_s(Fb[fb + 200]) * cf + tv;
      ov.z = xv.z + bf2f_s(Fb[fb + 400]) * cf + tv;
      ov.w = xv.w + bf2f_s(Fb[fb + 600]) * cf + tv;
      *reinterpret_cast<float4*>(og + sliceBase + c * HWc + w4 * 4) = ov;
    }
  }
}

// -------------------------------------------------------------------- host ---
extern "C" void kernel_launch(void* const* d_in, const int* in_sizes, int n_in,
                              void* d_out, int out_size, void* d_ws, size_t ws_size,
                              hipStream_t stream)
{
  const float* t    = (const float*)d_in[0];
  const float* x_l  = (const float*)d_in[1];
  const float* x_r  = (const float*)d_in[2];
  const float* lnwl = (const float*)d_in[3];
  const float* lnbl = (const float*)d_in[4];
  const float* lnwr = (const float*)d_in[5];
  const float* lnbr = (const float*)d_in[6];
  const float* Wl1  = (const float*)d_in[7];
  const float* bl1  = (const float*)d_in[8];
  const float* Wr1  = (const float*)d_in[9];
  const float* br1  = (const float*)d_in[10];
  const float* Wl2  = (const float*)d_in[11];
  const float* bl2  = (const float*)d_in[12];
  const float* Wr2  = (const float*)d_in[13];
  const float* br2  = (const float*)d_in[14];
  const float* beta = (const float*)d_in[15];
  const float* gamma= (const float*)d_in[16];
  const float* Wt   = (const float*)d_in[17];
  const float* bt   = (const float*)d_in[18];
  float* out = (float*)d_out;

  char* ws = (char*)d_ws;
  short* W1l_b = (short*)ws;
  short* W1r_b = W1l_b + 36864;
  short* W2l_b = W1r_b + 36864;
  short* W2r_b = W2l_b + 36864;
  float* fws  = (float*)(ws + 4 * 73728);
  float* s1l  = fws;
  float* t1l  = fws + 192;
  float* s1r  = fws + 384;
  float* t1r  = fws + 576;
  float* temb = fws + 768;   // 3072 floats
  float* mt   = fws + 3840;  // 8192 floats

  setup1<<<610, 256, 0, stream>>>(t, lnwl, lnbl, lnwr, lnbr, Wl1, bl1, Wr1, br1,
                                  Wl2, Wr2, W1l_b, W1r_b, W2l_b, W2r_b,
                                  s1l, t1l, s1r, t1r, mt);
  setup2<<<12, 256, 0, stream>>>(mt, Wt, bt, temb);
  scam_main<<<1536, 768, 0, stream>>>(x_l, x_r, bl2, br2, beta, gamma,
                                      W1l_b, W1r_b, W2l_b, W2r_b,
                                      s1l, t1l, s1r, t1r, temb, out);
}